// Round 10
// baseline (407.322 us; speedup 1.0000x reference)
//
#include <hip/hip_runtime.h>
#include <cstdint>
#include <cstddef>

constexpr int NN = 50000;
constexpr int NE = 800000;

typedef short bf16x8 __attribute__((ext_vector_type(8)));
typedef short short4v __attribute__((ext_vector_type(4)));
typedef float f32x16 __attribute__((ext_vector_type(16)));
typedef _Float16 half4v __attribute__((ext_vector_type(4)));
typedef unsigned short ushort_t;

__device__ inline unsigned short f2bf(float f) {
  unsigned u = __float_as_uint(f);
  return (unsigned short)((u + 0x7FFFu + ((u >> 16) & 1u)) >> 16);
}
__device__ inline float bf2f(unsigned short h) {
  return __uint_as_float(((unsigned)h) << 16);
}
__device__ inline ushort_t f2h(float f) {
  _Float16 h = (_Float16)f;
  return __builtin_bit_cast(ushort_t, h);
}

// ---- pre-transform weights W[M][K] fp32 -> frag-order bf16 hi/lo -------------
// idx = ((cb*(K/16)+kb)*64 + l)*8 + j ; col = cb*32+(l&31); k = kb*16+((l>>5)&1)*8+j
__global__ void k_wconv(const float* __restrict__ W, short* __restrict__ Bh,
                        short* __restrict__ Bl, int M, int K, int total) {
  int idx = blockIdx.x * 256 + threadIdx.x;
  if (idx >= total) return;
  int j = idx & 7;
  int l = (idx >> 3) & 63;
  int blk = idx >> 9;
  int nKB = K >> 4;
  int cb = blk / nKB, kb = blk - cb * nKB;
  int col = cb * 32 + (l & 31);
  int k = kb * 16 + ((l >> 5) & 1) * 8 + j;
  float v = (col < M) ? W[(size_t)col * K + k] : 0.f;
  unsigned short h = f2bf(v);
  Bh[idx] = (short)h;
  Bl[idx] = (short)f2bf(v - bf2f(h));
}

// ---- split-bf16 MFMA GEMM, depth-2 A prefetch --------------------------------
// BM=64, BN=128, 512 thr = 8 waves (2 row x 4 col), per-wave 32x32, BK=BKT.
// Double-buffered LDS A-tile (hi/lo, fragment order). B frag-order in global
// (L2-hot), loaded in-phase. A global loads issued TWO K-steps ahead in two
// named register buffers (vinA/vinB, loop unrolled x2 so indices are static):
// issue->consume spans 2 MFMA phases + 2 barriers to cover ~900cy HBM latency.
template<int ACT, int H16, int BKT>
__global__ __launch_bounds__(512) void gemm_mfma(const float* __restrict__ A,
    const short* __restrict__ Bh, const short* __restrict__ Bl,
    const float* __restrict__ bias, float* __restrict__ C,
    ushort_t* __restrict__ C16, int N, int M, int K)
{
  constexpr int NKK = BKT / 16;     // 16-k blocks per step (2 or 4)
  constexpr int EPT = BKT / 8;      // k-elems per staging thread (4 or 8)
  __shared__ short Ah[2][2 * NKK * 512];
  __shared__ short Al[2][2 * NKK * 512];
  const int t = threadIdx.x;
  const int lane = t & 63;
  const int wid = t >> 6;
  const int wr = wid >> 2;           // 0..1 row-tile
  const int wc = wid & 3;            // 0..3 col-tile
  const int row0 = blockIdx.x * 64;
  const int col0 = blockIdx.y * 128;
  const int nKB = K >> 4;
  const int nK = K / BKT;

  // staging: thread handles EPT consecutive k of one row
  const int srow = t & 63;
  const int kq = (t >> 6) * EPT;
  const int sbase = ((srow >> 5) * NKK + (kq >> 4)) * 512 +
                    ((srow & 31) + 32 * ((kq >> 3) & 1)) * 8 + (kq & 7);
  const bool arow_ok = (row0 + srow) < N;
  const float* aptr = A + (size_t)(row0 + srow) * K + kq;

  const int cb = (col0 >> 5) + wc;

  f32x16 acc = {};

  float vinA[EPT], vinB[EPT];

  auto aload = [&](int ks, float* vin) {
    #pragma unroll
    for (int q = 0; q < EPT; ++q) vin[q] = 0.f;
    if (arow_ok && ks < nK) {
      #pragma unroll
      for (int q4 = 0; q4 < EPT / 4; ++q4) {
        float4 v = *(const float4*)(aptr + (size_t)ks * BKT + q4 * 4);
        vin[q4 * 4 + 0] = v.x; vin[q4 * 4 + 1] = v.y;
        vin[q4 * 4 + 2] = v.z; vin[q4 * 4 + 3] = v.w;
      }
    }
  };
  auto stage_write = [&](int buf, const float* vin) {
    if constexpr (EPT == 8) {
      bf16x8 hv, lv;
      #pragma unroll
      for (int q = 0; q < 8; ++q) {
        unsigned short h = f2bf(vin[q]);
        hv[q] = (short)h;
        lv[q] = (short)f2bf(vin[q] - bf2f(h));
      }
      *(bf16x8*)&Ah[buf][sbase] = hv;
      *(bf16x8*)&Al[buf][sbase] = lv;
    } else {
      short4v hv, lv;
      #pragma unroll
      for (int q = 0; q < 4; ++q) {
        unsigned short h = f2bf(vin[q]);
        hv[q] = (short)h;
        lv[q] = (short)f2bf(vin[q] - bf2f(h));
      }
      *(short4v*)&Ah[buf][sbase] = hv;
      *(short4v*)&Al[buf][sbase] = lv;
    }
  };
  auto mfma_step = [&](int buf, int ks) {
    #pragma unroll
    for (int kk = 0; kk < NKK; ++kk) {
      const int kbg = ks * NKK + kk;
      const size_t bo = ((size_t)(cb * nKB + kbg) * 64 + lane) * 8;
      bf16x8 bh = *(const bf16x8*)&Bh[bo];
      bf16x8 bl = *(const bf16x8*)&Bl[bo];
      bf16x8 ah = *(const bf16x8*)&Ah[buf][(wr * NKK + kk) * 512 + lane * 8];
      bf16x8 al = *(const bf16x8*)&Al[buf][(wr * NKK + kk) * 512 + lane * 8];
      acc = __builtin_amdgcn_mfma_f32_32x32x16_bf16(ah, bh, acc, 0, 0, 0);
      acc = __builtin_amdgcn_mfma_f32_32x32x16_bf16(al, bh, acc, 0, 0, 0);
      acc = __builtin_amdgcn_mfma_f32_32x32x16_bf16(ah, bl, acc, 0, 0, 0);
    }
  };

  // prologue: stage step 0; preload steps 1 (vinA) and 2 (vinB)
  aload(0, vinA);
  stage_write(0, vinA);
  aload(1, vinA);
  aload(2, vinB);
  __syncthreads();

  for (int ks = 0; ks < nK; ks += 2) {
    // even step: compute buf0, stage step ks+1 from vinA, refill vinA (ks+3)
    mfma_step(0, ks);
    if (ks + 1 < nK) stage_write(1, vinA);
    aload(ks + 3, vinA);
    __syncthreads();
    // odd step
    if (ks + 1 < nK) {
      mfma_step(1, ks + 1);
      if (ks + 2 < nK) stage_write(0, vinB);
      aload(ks + 4, vinB);
      __syncthreads();
    }
  }

  // epilogue: D layout col=lane&31, row=(reg&3)+8*(reg>>2)+4*(lane>>5)
  int cc = col0 + wc * 32 + (lane & 31);
  float bv = (cc < M) ? bias[cc] : 0.f;
  #pragma unroll
  for (int r = 0; r < 16; ++r) {
    int rr = row0 + wr * 32 + (r & 3) + 8 * (r >> 2) + 4 * (lane >> 5);
    if (rr < N && cc < M) {
      float v = acc[r] + bv;
      if (ACT) v = v > 0.f ? v : (__expf(v) - 1.f);
      if (H16) C16[(size_t)rr * M + cc] = f2h(v);
      else     C[(size_t)rr * M + cc] = v;
    }
  }
}

// ---------------- CSR build (dst-sorted edge permutation) ---------------------
__global__ void k_degree(const int* __restrict__ ei, int* __restrict__ deg) {
  int e = blockIdx.x * 256 + threadIdx.x;
  if (e < NE) atomicAdd(&deg[ei[NE + e]], 1);
}

__global__ __launch_bounds__(256) void k_scan1(const int* __restrict__ deg,
    int* __restrict__ rowstart, int* __restrict__ blocksum) {
  __shared__ int sm[256];
  int b = blockIdx.x, t = threadIdx.x;
  int i = b * 256 + t;
  int v = (i < NN) ? deg[i] : 0;
  sm[t] = v;
  __syncthreads();
  #pragma unroll
  for (int off = 1; off < 256; off <<= 1) {
    int u = (t >= off) ? sm[t - off] : 0;
    __syncthreads();
    sm[t] += u;
    __syncthreads();
  }
  if (i < NN) rowstart[i + 1] = sm[t];
  if (t == 255) blocksum[b] = sm[255];
}

__global__ __launch_bounds__(256) void k_scan2(int* __restrict__ blocksum, int nb) {
  __shared__ int sm[256];
  int t = threadIdx.x;
  int v = (t < nb) ? blocksum[t] : 0;
  sm[t] = v;
  __syncthreads();
  #pragma unroll
  for (int off = 1; off < 256; off <<= 1) {
    int u = (t >= off) ? sm[t - off] : 0;
    __syncthreads();
    sm[t] += u;
    __syncthreads();
  }
  if (t < nb) blocksum[t] = (t == 0) ? 0 : sm[t - 1];
}

__global__ __launch_bounds__(256) void k_scan3(int* __restrict__ rowstart,
    const int* __restrict__ blocksum) {
  int b = blockIdx.x, t = threadIdx.x;
  int i = b * 256 + t;
  if (i == 0) rowstart[0] = 0;
  if (i < NN) rowstart[i + 1] += blocksum[b];
}

__global__ void k_scatter(const int* __restrict__ ei, const int* __restrict__ rowstart,
                          int* __restrict__ cursor, int* __restrict__ srcp) {
  int e = blockIdx.x * 256 + threadIdx.x;
  if (e >= NE) return;
  int s = ei[e], d = ei[NE + e];
  int pos = rowstart[d] + atomicAdd(&cursor[d], 1);
  srcp[pos] = s;
}

// -------- fused GATv2 edge+node, channel-packed, 8-edge pipelined -------------
// lane c (0..31) owns channels 4c..4c+3 (head c>>3); butterfly xor 1,2,4.
// Block = 256 thr = 8 nodes. Coalesced float4 output.
__global__ __launch_bounds__(256) void k_gat(const ushort_t* __restrict__ xl,
    const float* __restrict__ xr, const int* __restrict__ srcp,
    const int* __restrict__ rowstart, const float* __restrict__ att,
    const float* __restrict__ bias, float* __restrict__ out)
{
  const int g = threadIdx.x >> 5;
  const int c = threadIdx.x & 31;
  const int n = blockIdx.x * 8 + g;
  const int r0 = rowstart[n], r1 = rowstart[n + 1];
  const float4 xrv = *(const float4*)(xr + (size_t)n * 128 + 4 * c);
  const float4 atv = *(const float4*)(att + 4 * c);

  float m = -1e30f, ssum = 0.f;
  float a0 = 0.f, a1 = 0.f, a2 = 0.f, a3 = 0.f;

  auto lg = [&](int s, float4& xs) -> float {
    half4v hv = *(const half4v*)(xl + (size_t)s * 128 + 4 * c);
    xs.x = (float)hv[0]; xs.y = (float)hv[1];
    xs.z = (float)hv[2]; xs.w = (float)hv[3];
    float u0 = xs.x + xrv.x; u0 = fmaxf(u0, 0.2f * u0);
    float u1 = xs.y + xrv.y; u1 = fmaxf(u1, 0.2f * u1);
    float u2 = xs.z + xrv.z; u2 = fmaxf(u2, 0.2f * u2);
    float u3 = xs.w + xrv.w; u3 = fmaxf(u3, 0.2f * u3);
    float l = u0 * atv.x + u1 * atv.y + u2 * atv.z + u3 * atv.w;
    l += __shfl_xor(l, 1);
    l += __shfl_xor(l, 2);
    l += __shfl_xor(l, 4);
    return l;
  };

  int j = r0;
  for (; j + 8 <= r1; j += 8) {
    int s0 = srcp[j],     s1 = srcp[j + 1], s2 = srcp[j + 2], s3 = srcp[j + 3];
    int s4 = srcp[j + 4], s5 = srcp[j + 5], s6 = srcp[j + 6], s7 = srcp[j + 7];
    float4 x0, x1, x2, x3, x4, x5, x6, x7;
    float l0 = lg(s0, x0), l1 = lg(s1, x1), l2 = lg(s2, x2), l3 = lg(s3, x3);
    float l4 = lg(s4, x4), l5 = lg(s5, x5), l6 = lg(s6, x6), l7 = lg(s7, x7);
    float mloc = fmaxf(fmaxf(fmaxf(l0, l1), fmaxf(l2, l3)),
                       fmaxf(fmaxf(l4, l5), fmaxf(l6, l7)));
    float mn = fmaxf(m, mloc);
    float sc = __expf(m - mn);
    float p0 = __expf(l0 - mn), p1 = __expf(l1 - mn);
    float p2 = __expf(l2 - mn), p3 = __expf(l3 - mn);
    float p4 = __expf(l4 - mn), p5 = __expf(l5 - mn);
    float p6 = __expf(l6 - mn), p7 = __expf(l7 - mn);
    ssum = ssum * sc + (((p0 + p1) + (p2 + p3)) + ((p4 + p5) + (p6 + p7)));
    a0 = a0 * sc + (((p0 * x0.x + p1 * x1.x) + (p2 * x2.x + p3 * x3.x)) +
                    ((p4 * x4.x + p5 * x5.x) + (p6 * x6.x + p7 * x7.x)));
    a1 = a1 * sc + (((p0 * x0.y + p1 * x1.y) + (p2 * x2.y + p3 * x3.y)) +
                    ((p4 * x4.y + p5 * x5.y) + (p6 * x6.y + p7 * x7.y)));
    a2 = a2 * sc + (((p0 * x0.z + p1 * x1.z) + (p2 * x2.z + p3 * x3.z)) +
                    ((p4 * x4.z + p5 * x5.z) + (p6 * x6.z + p7 * x7.z)));
    a3 = a3 * sc + (((p0 * x0.w + p1 * x1.w) + (p2 * x2.w + p3 * x3.w)) +
                    ((p4 * x4.w + p5 * x5.w) + (p6 * x6.w + p7 * x7.w)));
    m = mn;
  }
  for (; j + 4 <= r1; j += 4) {
    int s0 = srcp[j], s1 = srcp[j + 1], s2 = srcp[j + 2], s3 = srcp[j + 3];
    float4 x0, x1, x2, x3;
    float l0 = lg(s0, x0), l1 = lg(s1, x1), l2 = lg(s2, x2), l3 = lg(s3, x3);
    float mloc = fmaxf(fmaxf(l0, l1), fmaxf(l2, l3));
    float mn = fmaxf(m, mloc);
    float sc = __expf(m - mn);
    float p0 = __expf(l0 - mn), p1 = __expf(l1 - mn);
    float p2 = __expf(l2 - mn), p3 = __expf(l3 - mn);
    ssum = ssum * sc + ((p0 + p1) + (p2 + p3));
    a0 = a0 * sc + (p0 * x0.x + p1 * x1.x) + (p2 * x2.x + p3 * x3.x);
    a1 = a1 * sc + (p0 * x0.y + p1 * x1.y) + (p2 * x2.y + p3 * x3.y);
    a2 = a2 * sc + (p0 * x0.z + p1 * x1.z) + (p2 * x2.z + p3 * x3.z);
    a3 = a3 * sc + (p0 * x0.w + p1 * x1.w) + (p2 * x2.w + p3 * x3.w);
    m = mn;
  }
  for (; j < r1; ++j) {
    float4 xs;
    float l = lg(srcp[j], xs);
    float mn = fmaxf(m, l);
    float sc = __expf(m - mn);
    float p = __expf(l - mn);
    ssum = ssum * sc + p;
    a0 = a0 * sc + p * xs.x;
    a1 = a1 * sc + p * xs.y;
    a2 = a2 * sc + p * xs.z;
    a3 = a3 * sc + p * xs.w;
    m = mn;
  }

  const float4 bv = *(const float4*)(bias + 4 * c);
  float rinv = 1.f / (ssum + 1e-16f);
  float o0 = a0 * rinv + bv.x;
  float o1 = a1 * rinv + bv.y;
  float o2 = a2 * rinv + bv.z;
  float o3 = a3 * rinv + bv.w;
  o0 = o0 > 0.f ? o0 : (__expf(o0) - 1.f);
  o1 = o1 > 0.f ? o1 : (__expf(o1) - 1.f);
  o2 = o2 > 0.f ? o2 : (__expf(o2) - 1.f);
  o3 = o3 > 0.f ? o3 : (__expf(o3) - 1.f);
  *(float4*)(out + (size_t)n * 128 + 4 * c) = make_float4(o0, o1, o2, o3);
}

__global__ void k_report_ws(float* out, int out_size, float wsz) {
  int i = blockIdx.x * 256 + threadIdx.x;
  if (i < out_size) out[i] = (i == 0) ? wsz : 0.f;
}

// -----------------------------------------------------------------------------
extern "C" void kernel_launch(void* const* d_in, const int* in_sizes, int n_in,
                              void* d_out, int out_size, void* d_ws, size_t ws_size,
                              hipStream_t stream)
{
  const float* x    = (const float*)d_in[0];
  const int*   ei   = (const int*)d_in[1];     // int32 [2,E] row-major
  const float* Wp   = (const float*)d_in[2];  const float* bp    = (const float*)d_in[3];
  const float* Wl1  = (const float*)d_in[4];  const float* bl1   = (const float*)d_in[5];
  const float* Wr1  = (const float*)d_in[6];  const float* br1   = (const float*)d_in[7];
  const float* att1 = (const float*)d_in[8];  const float* bias1 = (const float*)d_in[9];
  const float* Wl2  = (const float*)d_in[10]; const float* bl2   = (const float*)d_in[11];
  const float* Wr2  = (const float*)d_in[12]; const float* br2   = (const float*)d_in[13];
  const float* att2 = (const float*)d_in[14]; const float* bias2 = (const float*)d_in[15];
  const float* W1   = (const float*)d_in[16]; const float* b1    = (const float*)d_in[17];
  const float* W2   = (const float*)d_in[18]; const float* b2    = (const float*)d_in[19];
  float* out = (float*)d_out;

  constexpr size_t NEED = 122300000;
  if (ws_size < NEED) {
    k_report_ws<<<(out_size + 255) / 256, 256, 0, stream>>>(out, out_size, (float)ws_size);
    return;
  }
  char* ws = (char*)d_ws;
  float*    h0    = (float*)(ws + 0);             // 50000*256 f32
  float*    h1    = h0;                           // reuse
  float*    h2    = (float*)(ws + 25600000);
  ushort_t* xlh   = (ushort_t*)(ws + 51200000);   // fp16 mirror, 12.8 MB
  float*    xr    = (float*)(ws + 76800000);
  float*    h3    = (float*)(ws + 102400000);     // 50000*32
  short*    wb    = (short*)(ws + 108800000);     // weight hi/lo frag buffers (<1MB)
  int*      srcp  = (int*)(ws + 115200000);
  int*      deg   = (int*)(ws + 121600000);
  int*      curs  = (int*)(ws + 121800000);
  int*      rowst = (int*)(ws + 122000000);
  int*      bsum  = (int*)(ws + 122250000);

  short* Wph  = wb;            short* Wpl  = wb + 131072;
  short* Wl1h = wb + 262144;   short* Wl1l = wb + 294912;
  short* Wr1h = wb + 327680;   short* Wr1l = wb + 360448;
  short* Wl2h = wb + 393216;   short* Wl2l = wb + 409600;
  short* Wr2h = wb + 425984;   short* Wr2l = wb + 442368;
  short* W1h  = wb + 458752;   short* W1l  = wb + 475136;
  short* W2h  = wb + 491520;   short* W2l  = wb + 495616;

  hipMemsetAsync(deg,  0, NN*sizeof(int), stream);
  hipMemsetAsync(curs, 0, NN*sizeof(int), stream);

  k_wconv<<<(131072+255)/256, 256, 0, stream>>>(Wp,  Wph,  Wpl,  256, 512, 131072);
  k_wconv<<<(32768+255)/256,  256, 0, stream>>>(Wl1, Wl1h, Wl1l, 128, 256, 32768);
  k_wconv<<<(32768+255)/256,  256, 0, stream>>>(Wr1, Wr1h, Wr1l, 128, 256, 32768);
  k_wconv<<<(16384+255)/256,  256, 0, stream>>>(Wl2, Wl2h, Wl2l, 128, 128, 16384);
  k_wconv<<<(16384+255)/256,  256, 0, stream>>>(Wr2, Wr2h, Wr2l, 128, 128, 16384);
  k_wconv<<<(16384+255)/256,  256, 0, stream>>>(W1,  W1h,  W1l,  32,  128, 16384);
  k_wconv<<<(4096+255)/256,   256, 0, stream>>>(W2,  W2h,  W2l,  10,  32,  4096);

  constexpr int NB = (NN + 255) / 256;
  k_degree <<<(NE+255)/256, 256, 0, stream>>>(ei, deg);
  k_scan1  <<<NB, 256, 0, stream>>>(deg, rowst, bsum);
  k_scan2  <<<1, 256, 0, stream>>>(bsum, NB);
  k_scan3  <<<NB, 256, 0, stream>>>(rowst, bsum);
  k_scatter<<<(NE+255)/256, 256, 0, stream>>>(ei, rowst, curs, srcp);

  constexpr int GX = (NN + 63) / 64;  // 782

  // projection: h0 = elu(x @ Wp^T + bp), M=256, K=512
  gemm_mfma<1,0,64><<<dim3(GX, 2), 512, 0, stream>>>(x, Wph, Wpl, bp, h0, nullptr, NN, 256, 512);

  // GAT layer 1
  gemm_mfma<0,1,64><<<dim3(GX, 1), 512, 0, stream>>>(h0, Wl1h, Wl1l, bl1, nullptr, xlh, NN, 128, 256);
  gemm_mfma<0,0,64><<<dim3(GX, 1), 512, 0, stream>>>(h0, Wr1h, Wr1l, br1, xr, nullptr, NN, 128, 256);
  k_gat<<<NN/8, 256, 0, stream>>>(xlh, xr, srcp, rowst, att1, bias1, h1);

  // GAT layer 2
  gemm_mfma<0,1,64><<<dim3(GX, 1), 512, 0, stream>>>(h1, Wl2h, Wl2l, bl2, nullptr, xlh, NN, 128, 128);
  gemm_mfma<0,0,64><<<dim3(GX, 1), 512, 0, stream>>>(h1, Wr2h, Wr2l, br2, xr, nullptr, NN, 128, 128);
  k_gat<<<NN/8, 256, 0, stream>>>(xlh, xr, srcp, rowst, att2, bias2, h2);

  // head MLP
  gemm_mfma<1,0,64><<<dim3(GX, 1), 512, 0, stream>>>(h2, W1h, W1l, b1, h3, nullptr, NN, 32, 128);
  gemm_mfma<0,0,32><<<dim3(GX, 1), 512, 0, stream>>>(h3, W2h, W2l, b2, out, nullptr, NN, 10, 32);
}

// Round 11
// 371.558 us; speedup vs baseline: 1.0963x; 1.0963x over previous
//
#include <hip/hip_runtime.h>
#include <cstdint>
#include <cstddef>

constexpr int NN = 50000;
constexpr int NE = 800000;

typedef short bf16x8 __attribute__((ext_vector_type(8)));
typedef short short4v __attribute__((ext_vector_type(4)));
typedef float f32x16 __attribute__((ext_vector_type(16)));
typedef _Float16 half4v __attribute__((ext_vector_type(4)));
typedef unsigned short ushort_t;

__device__ inline unsigned short f2bf(float f) {
  unsigned u = __float_as_uint(f);
  return (unsigned short)((u + 0x7FFFu + ((u >> 16) & 1u)) >> 16);
}
__device__ inline float bf2f(unsigned short h) {
  return __uint_as_float(((unsigned)h) << 16);
}
__device__ inline ushort_t f2h(float f) {
  _Float16 h = (_Float16)f;
  return __builtin_bit_cast(ushort_t, h);
}

// ---- pre-transform weights W[M][K] fp32 -> frag-order bf16 hi/lo -------------
// idx = ((cb*(K/16)+kb)*64 + l)*8 + j ; col = cb*32+(l&31); k = kb*16+((l>>5)&1)*8+j
__global__ void k_wconv(const float* __restrict__ W, short* __restrict__ Bh,
                        short* __restrict__ Bl, int M, int K, int total) {
  int idx = blockIdx.x * 256 + threadIdx.x;
  if (idx >= total) return;
  int j = idx & 7;
  int l = (idx >> 3) & 63;
  int blk = idx >> 9;
  int nKB = K >> 4;
  int cb = blk / nKB, kb = blk - cb * nKB;
  int col = cb * 32 + (l & 31);
  int k = kb * 16 + ((l >> 5) & 1) * 8 + j;
  float v = (col < M) ? W[(size_t)col * K + k] : 0.f;
  unsigned short h = f2bf(v);
  Bh[idx] = (short)h;
  Bl[idx] = (short)f2bf(v - bf2f(h));
}

// ---- split-bf16 MFMA GEMM (r9 body: BK=BKT, depth-1 prefetch) ----------------
// BM=64, BN=128, 512 thr = 8 waves (2 row x 4 col), per-wave 32x32.
// OUTMODE: 0 = f32 to C; 1 = fp16 to C16; 3 = split (cc<128 -> fp16 C16 stride
// 128 with bias, else f32 C stride 128 with bias2) for fused [Wl;Wr] layers.
template<int ACT, int OUTMODE, int BKT>
__global__ __launch_bounds__(512) void gemm_mfma(const float* __restrict__ A,
    const short* __restrict__ Bh, const short* __restrict__ Bl,
    const float* __restrict__ bias, const float* __restrict__ bias2,
    float* __restrict__ C, ushort_t* __restrict__ C16, int N, int M, int K)
{
  constexpr int NKK = BKT / 16;
  constexpr int EPT = BKT / 8;
  __shared__ short Ah[2][2 * NKK * 512];
  __shared__ short Al[2][2 * NKK * 512];
  const int t = threadIdx.x;
  const int lane = t & 63;
  const int wid = t >> 6;
  const int wr = wid >> 2;
  const int wc = wid & 3;
  const int row0 = blockIdx.x * 64;
  const int col0 = blockIdx.y * 128;
  const int nKB = K >> 4;
  const int nK = K / BKT;

  const int srow = t & 63;
  const int kq = (t >> 6) * EPT;
  const int sbase = ((srow >> 5) * NKK + (kq >> 4)) * 512 +
                    ((srow & 31) + 32 * ((kq >> 3) & 1)) * 8 + (kq & 7);
  const bool arow_ok = (row0 + srow) < N;
  const float* aptr = A + (size_t)(row0 + srow) * K + kq;

  const int cb = (col0 >> 5) + wc;

  f32x16 acc = {};
  float vin[EPT];

  auto aload = [&](int ks) {
    #pragma unroll
    for (int q = 0; q < EPT; ++q) vin[q] = 0.f;
    if (arow_ok) {
      #pragma unroll
      for (int q4 = 0; q4 < EPT / 4; ++q4) {
        float4 v = *(const float4*)(aptr + (size_t)ks * BKT + q4 * 4);
        vin[q4 * 4 + 0] = v.x; vin[q4 * 4 + 1] = v.y;
        vin[q4 * 4 + 2] = v.z; vin[q4 * 4 + 3] = v.w;
      }
    }
  };
  auto stage_write = [&](int buf) {
    if constexpr (EPT == 8) {
      bf16x8 hv, lv;
      #pragma unroll
      for (int q = 0; q < 8; ++q) {
        unsigned short h = f2bf(vin[q]);
        hv[q] = (short)h;
        lv[q] = (short)f2bf(vin[q] - bf2f(h));
      }
      *(bf16x8*)&Ah[buf][sbase] = hv;
      *(bf16x8*)&Al[buf][sbase] = lv;
    } else {
      short4v hv, lv;
      #pragma unroll
      for (int q = 0; q < 4; ++q) {
        unsigned short h = f2bf(vin[q]);
        hv[q] = (short)h;
        lv[q] = (short)f2bf(vin[q] - bf2f(h));
      }
      *(short4v*)&Ah[buf][sbase] = hv;
      *(short4v*)&Al[buf][sbase] = lv;
    }
  };

  aload(0);
  stage_write(0);
  __syncthreads();

  for (int ks = 0; ks < nK; ++ks) {
    const int cur = ks & 1;
    const int nxt = cur ^ 1;
    const bool have_next = (ks + 1 < nK);
    if (have_next) aload(ks + 1);

    #pragma unroll
    for (int kk = 0; kk < NKK; ++kk) {
      const int kbg = ks * NKK + kk;
      const size_t bo = ((size_t)(cb * nKB + kbg) * 64 + lane) * 8;
      bf16x8 bh = *(const bf16x8*)&Bh[bo];
      bf16x8 bl = *(const bf16x8*)&Bl[bo];
      bf16x8 ah = *(const bf16x8*)&Ah[cur][(wr * NKK + kk) * 512 + lane * 8];
      bf16x8 al = *(const bf16x8*)&Al[cur][(wr * NKK + kk) * 512 + lane * 8];
      acc = __builtin_amdgcn_mfma_f32_32x32x16_bf16(ah, bh, acc, 0, 0, 0);
      acc = __builtin_amdgcn_mfma_f32_32x32x16_bf16(al, bh, acc, 0, 0, 0);
      acc = __builtin_amdgcn_mfma_f32_32x32x16_bf16(ah, bl, acc, 0, 0, 0);
    }

    if (have_next) stage_write(nxt);
    __syncthreads();
  }

  // epilogue: D layout col=lane&31, row=(reg&3)+8*(reg>>2)+4*(lane>>5)
  int cc = col0 + wc * 32 + (lane & 31);
  float bv;
  if (OUTMODE == 3) bv = (cc < 128) ? bias[cc] : bias2[cc - 128];
  else              bv = (cc < M) ? bias[cc] : 0.f;
  #pragma unroll
  for (int r = 0; r < 16; ++r) {
    int rr = row0 + wr * 32 + (r & 3) + 8 * (r >> 2) + 4 * (lane >> 5);
    if (rr < N && cc < M) {
      float v = acc[r] + bv;
      if (ACT) v = v > 0.f ? v : (__expf(v) - 1.f);
      if (OUTMODE == 0)      C[(size_t)rr * M + cc] = v;
      else if (OUTMODE == 1) C16[(size_t)rr * M + cc] = f2h(v);
      else {  // split
        if (cc < 128) C16[(size_t)rr * 128 + cc] = f2h(v);
        else          C[(size_t)rr * 128 + (cc - 128)] = v;
      }
    }
  }
}

// ---------------- CSR build (dst-sorted edge permutation) ---------------------
__global__ void k_degree(const int* __restrict__ ei, int* __restrict__ deg) {
  int e = blockIdx.x * 256 + threadIdx.x;
  if (e < NE) atomicAdd(&deg[ei[NE + e]], 1);
}

__global__ __launch_bounds__(256) void k_scan1(const int* __restrict__ deg,
    int* __restrict__ rowstart, int* __restrict__ blocksum) {
  __shared__ int sm[256];
  int b = blockIdx.x, t = threadIdx.x;
  int i = b * 256 + t;
  int v = (i < NN) ? deg[i] : 0;
  sm[t] = v;
  __syncthreads();
  #pragma unroll
  for (int off = 1; off < 256; off <<= 1) {
    int u = (t >= off) ? sm[t - off] : 0;
    __syncthreads();
    sm[t] += u;
    __syncthreads();
  }
  if (i < NN) rowstart[i + 1] = sm[t];
  if (t == 255) blocksum[b] = sm[255];
}

__global__ __launch_bounds__(256) void k_scan2(int* __restrict__ blocksum, int nb) {
  __shared__ int sm[256];
  int t = threadIdx.x;
  int v = (t < nb) ? blocksum[t] : 0;
  sm[t] = v;
  __syncthreads();
  #pragma unroll
  for (int off = 1; off < 256; off <<= 1) {
    int u = (t >= off) ? sm[t - off] : 0;
    __syncthreads();
    sm[t] += u;
    __syncthreads();
  }
  if (t < nb) blocksum[t] = (t == 0) ? 0 : sm[t - 1];
}

__global__ __launch_bounds__(256) void k_scan3(int* __restrict__ rowstart,
    const int* __restrict__ blocksum) {
  int b = blockIdx.x, t = threadIdx.x;
  int i = b * 256 + t;
  if (i == 0) rowstart[0] = 0;
  if (i < NN) rowstart[i + 1] += blocksum[b];
}

__global__ void k_scatter(const int* __restrict__ ei, const int* __restrict__ rowstart,
                          int* __restrict__ cursor, int* __restrict__ srcp) {
  int e = blockIdx.x * 256 + threadIdx.x;
  if (e >= NE) return;
  int s = ei[e], d = ei[NE + e];
  int pos = rowstart[d] + atomicAdd(&cursor[d], 1);
  srcp[pos] = s;
}

// -------- fused GATv2 edge+node, channel-packed, 8-edge pipelined -------------
__global__ __launch_bounds__(256) void k_gat(const ushort_t* __restrict__ xl,
    const float* __restrict__ xr, const int* __restrict__ srcp,
    const int* __restrict__ rowstart, const float* __restrict__ att,
    const float* __restrict__ bias, float* __restrict__ out)
{
  const int g = threadIdx.x >> 5;
  const int c = threadIdx.x & 31;
  const int n = blockIdx.x * 8 + g;
  const int r0 = rowstart[n], r1 = rowstart[n + 1];
  const float4 xrv = *(const float4*)(xr + (size_t)n * 128 + 4 * c);
  const float4 atv = *(const float4*)(att + 4 * c);

  float m = -1e30f, ssum = 0.f;
  float a0 = 0.f, a1 = 0.f, a2 = 0.f, a3 = 0.f;

  auto lg = [&](int s, float4& xs) -> float {
    half4v hv = *(const half4v*)(xl + (size_t)s * 128 + 4 * c);
    xs.x = (float)hv[0]; xs.y = (float)hv[1];
    xs.z = (float)hv[2]; xs.w = (float)hv[3];
    float u0 = xs.x + xrv.x; u0 = fmaxf(u0, 0.2f * u0);
    float u1 = xs.y + xrv.y; u1 = fmaxf(u1, 0.2f * u1);
    float u2 = xs.z + xrv.z; u2 = fmaxf(u2, 0.2f * u2);
    float u3 = xs.w + xrv.w; u3 = fmaxf(u3, 0.2f * u3);
    float l = u0 * atv.x + u1 * atv.y + u2 * atv.z + u3 * atv.w;
    l += __shfl_xor(l, 1);
    l += __shfl_xor(l, 2);
    l += __shfl_xor(l, 4);
    return l;
  };

  int j = r0;
  for (; j + 8 <= r1; j += 8) {
    int s0 = srcp[j],     s1 = srcp[j + 1], s2 = srcp[j + 2], s3 = srcp[j + 3];
    int s4 = srcp[j + 4], s5 = srcp[j + 5], s6 = srcp[j + 6], s7 = srcp[j + 7];
    float4 x0, x1, x2, x3, x4, x5, x6, x7;
    float l0 = lg(s0, x0), l1 = lg(s1, x1), l2 = lg(s2, x2), l3 = lg(s3, x3);
    float l4 = lg(s4, x4), l5 = lg(s5, x5), l6 = lg(s6, x6), l7 = lg(s7, x7);
    float mloc = fmaxf(fmaxf(fmaxf(l0, l1), fmaxf(l2, l3)),
                       fmaxf(fmaxf(l4, l5), fmaxf(l6, l7)));
    float mn = fmaxf(m, mloc);
    float sc = __expf(m - mn);
    float p0 = __expf(l0 - mn), p1 = __expf(l1 - mn);
    float p2 = __expf(l2 - mn), p3 = __expf(l3 - mn);
    float p4 = __expf(l4 - mn), p5 = __expf(l5 - mn);
    float p6 = __expf(l6 - mn), p7 = __expf(l7 - mn);
    ssum = ssum * sc + (((p0 + p1) + (p2 + p3)) + ((p4 + p5) + (p6 + p7)));
    a0 = a0 * sc + (((p0 * x0.x + p1 * x1.x) + (p2 * x2.x + p3 * x3.x)) +
                    ((p4 * x4.x + p5 * x5.x) + (p6 * x6.x + p7 * x7.x)));
    a1 = a1 * sc + (((p0 * x0.y + p1 * x1.y) + (p2 * x2.y + p3 * x3.y)) +
                    ((p4 * x4.y + p5 * x5.y) + (p6 * x6.y + p7 * x7.y)));
    a2 = a2 * sc + (((p0 * x0.z + p1 * x1.z) + (p2 * x2.z + p3 * x3.z)) +
                    ((p4 * x4.z + p5 * x5.z) + (p6 * x6.z + p7 * x7.z)));
    a3 = a3 * sc + (((p0 * x0.w + p1 * x1.w) + (p2 * x2.w + p3 * x3.w)) +
                    ((p4 * x4.w + p5 * x5.w) + (p6 * x6.w + p7 * x7.w)));
    m = mn;
  }
  for (; j + 4 <= r1; j += 4) {
    int s0 = srcp[j], s1 = srcp[j + 1], s2 = srcp[j + 2], s3 = srcp[j + 3];
    float4 x0, x1, x2, x3;
    float l0 = lg(s0, x0), l1 = lg(s1, x1), l2 = lg(s2, x2), l3 = lg(s3, x3);
    float mloc = fmaxf(fmaxf(l0, l1), fmaxf(l2, l3));
    float mn = fmaxf(m, mloc);
    float sc = __expf(m - mn);
    float p0 = __expf(l0 - mn), p1 = __expf(l1 - mn);
    float p2 = __expf(l2 - mn), p3 = __expf(l3 - mn);
    ssum = ssum * sc + ((p0 + p1) + (p2 + p3));
    a0 = a0 * sc + (p0 * x0.x + p1 * x1.x) + (p2 * x2.x + p3 * x3.x);
    a1 = a1 * sc + (p0 * x0.y + p1 * x1.y) + (p2 * x2.y + p3 * x3.y);
    a2 = a2 * sc + (p0 * x0.z + p1 * x1.z) + (p2 * x2.z + p3 * x3.z);
    a3 = a3 * sc + (p0 * x0.w + p1 * x1.w) + (p2 * x2.w + p3 * x3.w);
    m = mn;
  }
  for (; j < r1; ++j) {
    float4 xs;
    float l = lg(srcp[j], xs);
    float mn = fmaxf(m, l);
    float sc = __expf(m - mn);
    float p = __expf(l - mn);
    ssum = ssum * sc + p;
    a0 = a0 * sc + p * xs.x;
    a1 = a1 * sc + p * xs.y;
    a2 = a2 * sc + p * xs.z;
    a3 = a3 * sc + p * xs.w;
    m = mn;
  }

  const float4 bv = *(const float4*)(bias + 4 * c);
  float rinv = 1.f / (ssum + 1e-16f);
  float o0 = a0 * rinv + bv.x;
  float o1 = a1 * rinv + bv.y;
  float o2 = a2 * rinv + bv.z;
  float o3 = a3 * rinv + bv.w;
  o0 = o0 > 0.f ? o0 : (__expf(o0) - 1.f);
  o1 = o1 > 0.f ? o1 : (__expf(o1) - 1.f);
  o2 = o2 > 0.f ? o2 : (__expf(o2) - 1.f);
  o3 = o3 > 0.f ? o3 : (__expf(o3) - 1.f);
  *(float4*)(out + (size_t)n * 128 + 4 * c) = make_float4(o0, o1, o2, o3);
}

__global__ void k_report_ws(float* out, int out_size, float wsz) {
  int i = blockIdx.x * 256 + threadIdx.x;
  if (i < out_size) out[i] = (i == 0) ? wsz : 0.f;
}

// -----------------------------------------------------------------------------
extern "C" void kernel_launch(void* const* d_in, const int* in_sizes, int n_in,
                              void* d_out, int out_size, void* d_ws, size_t ws_size,
                              hipStream_t stream)
{
  const float* x    = (const float*)d_in[0];
  const int*   ei   = (const int*)d_in[1];     // int32 [2,E] row-major
  const float* Wp   = (const float*)d_in[2];  const float* bp    = (const float*)d_in[3];
  const float* Wl1  = (const float*)d_in[4];  const float* bl1   = (const float*)d_in[5];
  const float* Wr1  = (const float*)d_in[6];  const float* br1   = (const float*)d_in[7];
  const float* att1 = (const float*)d_in[8];  const float* bias1 = (const float*)d_in[9];
  const float* Wl2  = (const float*)d_in[10]; const float* bl2   = (const float*)d_in[11];
  const float* Wr2  = (const float*)d_in[12]; const float* br2   = (const float*)d_in[13];
  const float* att2 = (const float*)d_in[14]; const float* bias2 = (const float*)d_in[15];
  const float* W1   = (const float*)d_in[16]; const float* b1    = (const float*)d_in[17];
  const float* W2   = (const float*)d_in[18]; const float* b2    = (const float*)d_in[19];
  float* out = (float*)d_out;

  constexpr size_t NEED = 122300000;
  if (ws_size < NEED) {
    k_report_ws<<<(out_size + 255) / 256, 256, 0, stream>>>(out, out_size, (float)ws_size);
    return;
  }
  char* ws = (char*)d_ws;
  float*    h0    = (float*)(ws + 0);             // 50000*256 f32
  float*    h1    = h0;                           // reuse
  float*    h2    = (float*)(ws + 25600000);
  ushort_t* xlh   = (ushort_t*)(ws + 51200000);   // fp16 mirror, 12.8 MB
  float*    xr    = (float*)(ws + 76800000);
  float*    h3    = (float*)(ws + 102400000);     // 50000*32
  short*    wb    = (short*)(ws + 108800000);     // weight hi/lo frag buffers ~1MB
  int*      srcp  = (int*)(ws + 115200000);
  int*      deg   = (int*)(ws + 121600000);
  int*      curs  = (int*)(ws + 121800000);
  int*      rowst = (int*)(ws + 122000000);
  int*      bsum  = (int*)(ws + 122250000);

  // weight carve (element offsets in shorts)
  short* Wph  = wb;            short* Wpl  = wb + 131072;
  short* WB1h = wb + 262144;   short* WB1l = wb + 327680;   // 65536 each ([Wl1;Wr1])
  short* WB2h = wb + 393216;   short* WB2l = wb + 425984;   // 32768 each ([Wl2;Wr2])
  short* W1h  = wb + 458752;   short* W1l  = wb + 475136;   // 16384 each (padded)
  short* W2h  = wb + 491520;   short* W2l  = wb + 495616;   // 4096 each

  hipMemsetAsync(deg,  0, NN*sizeof(int), stream);
  hipMemsetAsync(curs, 0, NN*sizeof(int), stream);

  // weight pre-transform; fused layers concat col-blocks: Wl at cb0-3, Wr at cb4-7
  k_wconv<<<(131072+255)/256, 256, 0, stream>>>(Wp,  Wph,  Wpl,  256, 512, 131072);
  k_wconv<<<(32768+255)/256,  256, 0, stream>>>(Wl1, WB1h,        WB1l,        128, 256, 32768);
  k_wconv<<<(32768+255)/256,  256, 0, stream>>>(Wr1, WB1h + 32768, WB1l + 32768, 128, 256, 32768);
  k_wconv<<<(16384+255)/256,  256, 0, stream>>>(Wl2, WB2h,        WB2l,        128, 128, 16384);
  k_wconv<<<(16384+255)/256,  256, 0, stream>>>(Wr2, WB2h + 16384, WB2l + 16384, 128, 128, 16384);
  k_wconv<<<(16384+255)/256,  256, 0, stream>>>(W1,  W1h,  W1l,  32,  128, 16384);
  k_wconv<<<(4096+255)/256,   256, 0, stream>>>(W2,  W2h,  W2l,  10,  32,  4096);

  constexpr int NB = (NN + 255) / 256;
  k_degree <<<(NE+255)/256, 256, 0, stream>>>(ei, deg);
  k_scan1  <<<NB, 256, 0, stream>>>(deg, rowst, bsum);
  k_scan2  <<<1, 256, 0, stream>>>(bsum, NB);
  k_scan3  <<<NB, 256, 0, stream>>>(rowst, bsum);
  k_scatter<<<(NE+255)/256, 256, 0, stream>>>(ei, rowst, curs, srcp);

  constexpr int GX = (NN + 63) / 64;  // 782

  // projection: h0 = elu(x @ Wp^T + bp), M=256, K=512
  gemm_mfma<1,0,64><<<dim3(GX, 2), 512, 0, stream>>>(
      x, Wph, Wpl, bp, nullptr, h0, nullptr, NN, 256, 512);

  // GAT layer 1: fused [xl|xr] = h0 @ [Wl1;Wr1]^T, M=256, K=256
  gemm_mfma<0,3,64><<<dim3(GX, 2), 512, 0, stream>>>(
      h0, WB1h, WB1l, bl1, br1, xr, xlh, NN, 256, 256);
  k_gat<<<NN/8, 256, 0, stream>>>(xlh, xr, srcp, rowst, att1, bias1, h1);

  // GAT layer 2: fused, M=256, K=128
  gemm_mfma<0,3,64><<<dim3(GX, 2), 512, 0, stream>>>(
      h1, WB2h, WB2l, bl2, br2, xr, xlh, NN, 256, 128);
  k_gat<<<NN/8, 256, 0, stream>>>(xlh, xr, srcp, rowst, att2, bias2, h2);

  // head MLP
  gemm_mfma<1,0,64><<<dim3(GX, 1), 512, 0, stream>>>(
      h2, W1h, W1l, b1, nullptr, h3, nullptr, NN, 32, 128);
  gemm_mfma<0,0,32><<<dim3(GX, 1), 512, 0, stream>>>(
      h3, W2h, W2l, b2, nullptr, out, nullptr, NN, 10, 32);
}

// Round 12
// 302.854 us; speedup vs baseline: 1.3449x; 1.2269x over previous
//
#include <hip/hip_runtime.h>
#include <cstdint>
#include <cstddef>

constexpr int NN = 50000;
constexpr int NE = 800000;

typedef _Float16 half8 __attribute__((ext_vector_type(8)));
typedef _Float16 half4v __attribute__((ext_vector_type(4)));
typedef float f32x16 __attribute__((ext_vector_type(16)));
typedef unsigned short ushort_t;

__device__ inline ushort_t f2h(float f) {
  _Float16 h = (_Float16)f;
  return __builtin_bit_cast(ushort_t, h);
}

// ---- pre-transform weights W[M][K] fp32 -> frag-order fp16 -------------------
// idx = ((cb*(K/16)+kb)*64 + l)*8 + j ; col = cb*32+(l&31); k = kb*16+((l>>5)&1)*8+j
__global__ void k_wconv(const float* __restrict__ W, ushort_t* __restrict__ Bh,
                        int M, int K, int total) {
  int idx = blockIdx.x * 256 + threadIdx.x;
  if (idx >= total) return;
  int j = idx & 7;
  int l = (idx >> 3) & 63;
  int blk = idx >> 9;
  int nKB = K >> 4;
  int cb = blk / nKB, kb = blk - cb * nKB;
  int col = cb * 32 + (l & 31);
  int k = kb * 16 + ((l >> 5) & 1) * 8 + j;
  float v = (col < M) ? W[(size_t)col * K + k] : 0.f;
  Bh[idx] = f2h(v);
}

// ---- fp16 MFMA GEMM (1 MFMA per 16-k block), depth-1 prefetch ----------------
// BM=64, BN=128, 512 thr = 8 waves (2 row x 4 col), per-wave 32x32, BK=BKT.
// OUTMODE: 0 = f32 to C; 1 = fp16 to C16; 3 = split (cc<128 -> fp16 C16 stride
// 128 with bias, else f32 C stride 128 with bias2) for fused [Wl;Wr] layers.
template<int ACT, int OUTMODE, int BKT>
__global__ __launch_bounds__(512) void gemm_mfma(const float* __restrict__ A,
    const ushort_t* __restrict__ Bh,
    const float* __restrict__ bias, const float* __restrict__ bias2,
    float* __restrict__ C, ushort_t* __restrict__ C16, int N, int M, int K)
{
  constexpr int NKK = BKT / 16;     // 16-k blocks per step
  constexpr int EPT = BKT / 8;      // k-elems per staging thread (4 or 8)
  __shared__ ushort_t Ah[2][2 * NKK * 512];
  const int t = threadIdx.x;
  const int lane = t & 63;
  const int wid = t >> 6;
  const int wr = wid >> 2;
  const int wc = wid & 3;
  const int row0 = blockIdx.x * 64;
  const int col0 = blockIdx.y * 128;
  const int nKB = K >> 4;
  const int nK = K / BKT;

  const int srow = t & 63;
  const int kq = (t >> 6) * EPT;
  const int sbase = ((srow >> 5) * NKK + (kq >> 4)) * 512 +
                    ((srow & 31) + 32 * ((kq >> 3) & 1)) * 8 + (kq & 7);
  const bool arow_ok = (row0 + srow) < N;
  const float* aptr = A + (size_t)(row0 + srow) * K + kq;

  const int cb = (col0 >> 5) + wc;

  f32x16 acc = {};
  float vin[EPT];

  auto aload = [&](int ks) {
    #pragma unroll
    for (int q = 0; q < EPT; ++q) vin[q] = 0.f;
    if (arow_ok) {
      #pragma unroll
      for (int q4 = 0; q4 < EPT / 4; ++q4) {
        float4 v = *(const float4*)(aptr + (size_t)ks * BKT + q4 * 4);
        vin[q4 * 4 + 0] = v.x; vin[q4 * 4 + 1] = v.y;
        vin[q4 * 4 + 2] = v.z; vin[q4 * 4 + 3] = v.w;
      }
    }
  };
  auto stage_write = [&](int buf) {
    if constexpr (EPT == 8) {
      half8 hv;
      #pragma unroll
      for (int q = 0; q < 8; ++q) hv[q] = (_Float16)vin[q];
      *(half8*)&Ah[buf][sbase] = hv;
    } else {
      half4v hv;
      #pragma unroll
      for (int q = 0; q < 4; ++q) hv[q] = (_Float16)vin[q];
      *(half4v*)&Ah[buf][sbase] = hv;
    }
  };

  aload(0);
  stage_write(0);
  __syncthreads();

  for (int ks = 0; ks < nK; ++ks) {
    const int cur = ks & 1;
    const int nxt = cur ^ 1;
    const bool have_next = (ks + 1 < nK);
    if (have_next) aload(ks + 1);

    #pragma unroll
    for (int kk = 0; kk < NKK; ++kk) {
      const int kbg = ks * NKK + kk;
      const size_t bo = ((size_t)(cb * nKB + kbg) * 64 + lane) * 8;
      half8 bh = *(const half8*)(Bh + bo);
      half8 ah = *(const half8*)&Ah[cur][(wr * NKK + kk) * 512 + lane * 8];
      acc = __builtin_amdgcn_mfma_f32_32x32x16_f16(ah, bh, acc, 0, 0, 0);
    }

    if (have_next) stage_write(nxt);
    __syncthreads();
  }

  // epilogue: D layout col=lane&31, row=(reg&3)+8*(reg>>2)+4*(lane>>5)
  int cc = col0 + wc * 32 + (lane & 31);
  float bv;
  if (OUTMODE == 3) bv = (cc < 128) ? bias[cc] : bias2[cc - 128];
  else              bv = (cc < M) ? bias[cc] : 0.f;
  #pragma unroll
  for (int r = 0; r < 16; ++r) {
    int rr = row0 + wr * 32 + (r & 3) + 8 * (r >> 2) + 4 * (lane >> 5);
    if (rr < N && cc < M) {
      float v = acc[r] + bv;
      if (ACT) v = v > 0.f ? v : (__expf(v) - 1.f);
      if (OUTMODE == 0)      C[(size_t)rr * M + cc] = v;
      else if (OUTMODE == 1) C16[(size_t)rr * M + cc] = f2h(v);
      else {
        if (cc < 128) C16[(size_t)rr * 128 + cc] = f2h(v);
        else          C[(size_t)rr * 128 + (cc - 128)] = v;
      }
    }
  }
}

// ---------------- CSR build (dst-sorted edge permutation) ---------------------
// pass 1: degree count; atomicAdd's return value doubles as within-bucket rank
__global__ void k_degrank(const int* __restrict__ ei, int* __restrict__ deg,
                          int* __restrict__ rank) {
  int e = blockIdx.x * 256 + threadIdx.x;
  if (e >= NE) return;
  int d = ei[NE + e];
  rank[e] = atomicAdd(&deg[d], 1);
}

__global__ __launch_bounds__(256) void k_scan1(const int* __restrict__ deg,
    int* __restrict__ rowstart, int* __restrict__ blocksum) {
  __shared__ int sm[256];
  int b = blockIdx.x, t = threadIdx.x;
  int i = b * 256 + t;
  int v = (i < NN) ? deg[i] : 0;
  sm[t] = v;
  __syncthreads();
  #pragma unroll
  for (int off = 1; off < 256; off <<= 1) {
    int u = (t >= off) ? sm[t - off] : 0;
    __syncthreads();
    sm[t] += u;
    __syncthreads();
  }
  if (i < NN) rowstart[i + 1] = sm[t];
  if (t == 255) blocksum[b] = sm[255];
}

__global__ __launch_bounds__(256) void k_scan2(int* __restrict__ blocksum, int nb) {
  __shared__ int sm[256];
  int t = threadIdx.x;
  int v = (t < nb) ? blocksum[t] : 0;
  sm[t] = v;
  __syncthreads();
  #pragma unroll
  for (int off = 1; off < 256; off <<= 1) {
    int u = (t >= off) ? sm[t - off] : 0;
    __syncthreads();
    sm[t] += u;
    __syncthreads();
  }
  if (t < nb) blocksum[t] = (t == 0) ? 0 : sm[t - 1];
}

__global__ __launch_bounds__(256) void k_scan3(int* __restrict__ rowstart,
    const int* __restrict__ blocksum) {
  int b = blockIdx.x, t = threadIdx.x;
  int i = b * 256 + t;
  if (i == 0) rowstart[0] = 0;
  if (i < NN) rowstart[i + 1] += blocksum[b];
}

// pass 2: atomic-free scatter using precomputed ranks
__global__ void k_scatter(const int* __restrict__ ei, const int* __restrict__ rowstart,
                          const int* __restrict__ rank, int* __restrict__ srcp) {
  int e = blockIdx.x * 256 + threadIdx.x;
  if (e >= NE) return;
  int d = ei[NE + e];
  srcp[rowstart[d] + rank[e]] = ei[e];
}

// -------- fused GATv2 edge+node, channel-packed, 8-edge pipelined -------------
__global__ __launch_bounds__(256) void k_gat(const ushort_t* __restrict__ xl,
    const float* __restrict__ xr, const int* __restrict__ srcp,
    const int* __restrict__ rowstart, const float* __restrict__ att,
    const float* __restrict__ bias, float* __restrict__ out)
{
  const int g = threadIdx.x >> 5;
  const int c = threadIdx.x & 31;
  const int n = blockIdx.x * 8 + g;
  const int r0 = rowstart[n], r1 = rowstart[n + 1];
  const float4 xrv = *(const float4*)(xr + (size_t)n * 128 + 4 * c);
  const float4 atv = *(const float4*)(att + 4 * c);

  float m = -1e30f, ssum = 0.f;
  float a0 = 0.f, a1 = 0.f, a2 = 0.f, a3 = 0.f;

  auto lg = [&](int s, float4& xs) -> float {
    half4v hv = *(const half4v*)(xl + (size_t)s * 128 + 4 * c);
    xs.x = (float)hv[0]; xs.y = (float)hv[1];
    xs.z = (float)hv[2]; xs.w = (float)hv[3];
    float u0 = xs.x + xrv.x; u0 = fmaxf(u0, 0.2f * u0);
    float u1 = xs.y + xrv.y; u1 = fmaxf(u1, 0.2f * u1);
    float u2 = xs.z + xrv.z; u2 = fmaxf(u2, 0.2f * u2);
    float u3 = xs.w + xrv.w; u3 = fmaxf(u3, 0.2f * u3);
    float l = u0 * atv.x + u1 * atv.y + u2 * atv.z + u3 * atv.w;
    l += __shfl_xor(l, 1);
    l += __shfl_xor(l, 2);
    l += __shfl_xor(l, 4);
    return l;
  };

  int j = r0;
  for (; j + 8 <= r1; j += 8) {
    int s0 = srcp[j],     s1 = srcp[j + 1], s2 = srcp[j + 2], s3 = srcp[j + 3];
    int s4 = srcp[j + 4], s5 = srcp[j + 5], s6 = srcp[j + 6], s7 = srcp[j + 7];
    float4 x0, x1, x2, x3, x4, x5, x6, x7;
    float l0 = lg(s0, x0), l1 = lg(s1, x1), l2 = lg(s2, x2), l3 = lg(s3, x3);
    float l4 = lg(s4, x4), l5 = lg(s5, x5), l6 = lg(s6, x6), l7 = lg(s7, x7);
    float mloc = fmaxf(fmaxf(fmaxf(l0, l1), fmaxf(l2, l3)),
                       fmaxf(fmaxf(l4, l5), fmaxf(l6, l7)));
    float mn = fmaxf(m, mloc);
    float sc = __expf(m - mn);
    float p0 = __expf(l0 - mn), p1 = __expf(l1 - mn);
    float p2 = __expf(l2 - mn), p3 = __expf(l3 - mn);
    float p4 = __expf(l4 - mn), p5 = __expf(l5 - mn);
    float p6 = __expf(l6 - mn), p7 = __expf(l7 - mn);
    ssum = ssum * sc + (((p0 + p1) + (p2 + p3)) + ((p4 + p5) + (p6 + p7)));
    a0 = a0 * sc + (((p0 * x0.x + p1 * x1.x) + (p2 * x2.x + p3 * x3.x)) +
                    ((p4 * x4.x + p5 * x5.x) + (p6 * x6.x + p7 * x7.x)));
    a1 = a1 * sc + (((p0 * x0.y + p1 * x1.y) + (p2 * x2.y + p3 * x3.y)) +
                    ((p4 * x4.y + p5 * x5.y) + (p6 * x6.y + p7 * x7.y)));
    a2 = a2 * sc + (((p0 * x0.z + p1 * x1.z) + (p2 * x2.z + p3 * x3.z)) +
                    ((p4 * x4.z + p5 * x5.z) + (p6 * x6.z + p7 * x7.z)));
    a3 = a3 * sc + (((p0 * x0.w + p1 * x1.w) + (p2 * x2.w + p3 * x3.w)) +
                    ((p4 * x4.w + p5 * x5.w) + (p6 * x6.w + p7 * x7.w)));
    m = mn;
  }
  for (; j + 4 <= r1; j += 4) {
    int s0 = srcp[j], s1 = srcp[j + 1], s2 = srcp[j + 2], s3 = srcp[j + 3];
    float4 x0, x1, x2, x3;
    float l0 = lg(s0, x0), l1 = lg(s1, x1), l2 = lg(s2, x2), l3 = lg(s3, x3);
    float mloc = fmaxf(fmaxf(l0, l1), fmaxf(l2, l3));
    float mn = fmaxf(m, mloc);
    float sc = __expf(m - mn);
    float p0 = __expf(l0 - mn), p1 = __expf(l1 - mn);
    float p2 = __expf(l2 - mn), p3 = __expf(l3 - mn);
    ssum = ssum * sc + ((p0 + p1) + (p2 + p3));
    a0 = a0 * sc + (p0 * x0.x + p1 * x1.x) + (p2 * x2.x + p3 * x3.x);
    a1 = a1 * sc + (p0 * x0.y + p1 * x1.y) + (p2 * x2.y + p3 * x3.y);
    a2 = a2 * sc + (p0 * x0.z + p1 * x1.z) + (p2 * x2.z + p3 * x3.z);
    a3 = a3 * sc + (p0 * x0.w + p1 * x1.w) + (p2 * x2.w + p3 * x3.w);
    m = mn;
  }
  for (; j < r1; ++j) {
    float4 xs;
    float l = lg(srcp[j], xs);
    float mn = fmaxf(m, l);
    float sc = __expf(m - mn);
    float p = __expf(l - mn);
    ssum = ssum * sc + p;
    a0 = a0 * sc + p * xs.x;
    a1 = a1 * sc + p * xs.y;
    a2 = a2 * sc + p * xs.z;
    a3 = a3 * sc + p * xs.w;
    m = mn;
  }

  const float4 bv = *(const float4*)(bias + 4 * c);
  float rinv = 1.f / (ssum + 1e-16f);
  float o0 = a0 * rinv + bv.x;
  float o1 = a1 * rinv + bv.y;
  float o2 = a2 * rinv + bv.z;
  float o3 = a3 * rinv + bv.w;
  o0 = o0 > 0.f ? o0 : (__expf(o0) - 1.f);
  o1 = o1 > 0.f ? o1 : (__expf(o1) - 1.f);
  o2 = o2 > 0.f ? o2 : (__expf(o2) - 1.f);
  o3 = o3 > 0.f ? o3 : (__expf(o3) - 1.f);
  *(float4*)(out + (size_t)n * 128 + 4 * c) = make_float4(o0, o1, o2, o3);
}

__global__ void k_report_ws(float* out, int out_size, float wsz) {
  int i = blockIdx.x * 256 + threadIdx.x;
  if (i < out_size) out[i] = (i == 0) ? wsz : 0.f;
}

// -----------------------------------------------------------------------------
extern "C" void kernel_launch(void* const* d_in, const int* in_sizes, int n_in,
                              void* d_out, int out_size, void* d_ws, size_t ws_size,
                              hipStream_t stream)
{
  const float* x    = (const float*)d_in[0];
  const int*   ei   = (const int*)d_in[1];     // int32 [2,E] row-major
  const float* Wp   = (const float*)d_in[2];  const float* bp    = (const float*)d_in[3];
  const float* Wl1  = (const float*)d_in[4];  const float* bl1   = (const float*)d_in[5];
  const float* Wr1  = (const float*)d_in[6];  const float* br1   = (const float*)d_in[7];
  const float* att1 = (const float*)d_in[8];  const float* bias1 = (const float*)d_in[9];
  const float* Wl2  = (const float*)d_in[10]; const float* bl2   = (const float*)d_in[11];
  const float* Wr2  = (const float*)d_in[12]; const float* br2   = (const float*)d_in[13];
  const float* att2 = (const float*)d_in[14]; const float* bias2 = (const float*)d_in[15];
  const float* W1   = (const float*)d_in[16]; const float* b1    = (const float*)d_in[17];
  const float* W2   = (const float*)d_in[18]; const float* b2    = (const float*)d_in[19];
  float* out = (float*)d_out;

  constexpr size_t NEED = 122300000;
  if (ws_size < NEED) {
    k_report_ws<<<(out_size + 255) / 256, 256, 0, stream>>>(out, out_size, (float)ws_size);
    return;
  }
  char* ws = (char*)d_ws;
  float*    h0    = (float*)(ws + 0);             // 50000*256 f32
  float*    h1    = h0;                           // reuse
  float*    h2    = (float*)(ws + 25600000);
  ushort_t* xlh   = (ushort_t*)(ws + 51200000);   // fp16 mirror, 12.8 MB
  float*    xr    = (float*)(ws + 76800000);
  float*    h3    = (float*)(ws + 102400000);     // 50000*32
  ushort_t* wb    = (ushort_t*)(ws + 108800000);  // fp16 weight frag buffers
  int*      srcp  = (int*)(ws + 115200000);       // 3.2 MB
  int*      rank  = (int*)(ws + 118400000);       // 3.2 MB
  int*      deg   = (int*)(ws + 121600000);
  int*      rowst = (int*)(ws + 122000000);
  int*      bsum  = (int*)(ws + 122250000);

  // weight carve (element offsets in halves)
  ushort_t* Wph  = wb;             // 131072  (256x512)
  ushort_t* WB1h = wb + 131072;    // 65536   ([Wl1;Wr1], 2x 128x256)
  ushort_t* WB2h = wb + 196608;    // 32768   ([Wl2;Wr2], 2x 128x128)
  ushort_t* W1h  = wb + 229376;    // 4096    (32x128)
  ushort_t* W2h  = wb + 233472;    // 1024    (10->32 pad x32)

  hipMemsetAsync(deg, 0, NN * sizeof(int), stream);

  // weight pre-transform; fused layers concat col-blocks: Wl at cb0-3, Wr at cb4-7
  k_wconv<<<(131072+255)/256, 256, 0, stream>>>(Wp,  Wph,          256, 512, 131072);
  k_wconv<<<(32768+255)/256,  256, 0, stream>>>(Wl1, WB1h,         128, 256, 32768);
  k_wconv<<<(32768+255)/256,  256, 0, stream>>>(Wr1, WB1h + 32768, 128, 256, 32768);
  k_wconv<<<(16384+255)/256,  256, 0, stream>>>(Wl2, WB2h,         128, 128, 16384);
  k_wconv<<<(16384+255)/256,  256, 0, stream>>>(Wr2, WB2h + 16384, 128, 128, 16384);
  k_wconv<<<(4096+255)/256,   256, 0, stream>>>(W1,  W1h,          32,  128, 4096);
  k_wconv<<<(1024+255)/256,   256, 0, stream>>>(W2,  W2h,          10,  32,  1024);

  constexpr int NB = (NN + 255) / 256;
  k_degrank<<<(NE+255)/256, 256, 0, stream>>>(ei, deg, rank);
  k_scan1  <<<NB, 256, 0, stream>>>(deg, rowst, bsum);
  k_scan2  <<<1, 256, 0, stream>>>(bsum, NB);
  k_scan3  <<<NB, 256, 0, stream>>>(rowst, bsum);
  k_scatter<<<(NE+255)/256, 256, 0, stream>>>(ei, rowst, rank, srcp);

  constexpr int GX = (NN + 63) / 64;  // 782

  // projection: h0 = elu(x @ Wp^T + bp), M=256, K=512
  gemm_mfma<1,0,64><<<dim3(GX, 2), 512, 0, stream>>>(
      x, Wph, bp, nullptr, h0, nullptr, NN, 256, 512);

  // GAT layer 1: fused [xl|xr] = h0 @ [Wl1;Wr1]^T, M=256, K=256
  gemm_mfma<0,3,64><<<dim3(GX, 2), 512, 0, stream>>>(
      h0, WB1h, bl1, br1, xr, xlh, NN, 256, 256);
  k_gat<<<NN/8, 256, 0, stream>>>(xlh, xr, srcp, rowst, att1, bias1, h1);

  // GAT layer 2: fused, M=256, K=128
  gemm_mfma<0,3,64><<<dim3(GX, 2), 512, 0, stream>>>(
      h1, WB2h, bl2, br2, xr, xlh, NN, 256, 128);
  k_gat<<<NN/8, 256, 0, stream>>>(xlh, xr, srcp, rowst, att2, bias2, h2);

  // head MLP
  gemm_mfma<1,0,64><<<dim3(GX, 1), 512, 0, stream>>>(
      h2, W1h, b1, nullptr, h3, nullptr, NN, 32, 128);
  gemm_mfma<0,0,32><<<dim3(GX, 1), 512, 0, stream>>>(
      h3, W2h, b2, nullptr, out, nullptr, NN, 10, 32);
}

// Round 13
// 284.421 us; speedup vs baseline: 1.4321x; 1.0648x over previous
//
#include <hip/hip_runtime.h>
#include <cstdint>
#include <cstddef>

constexpr int NN = 50000;
constexpr int NE = 800000;

typedef _Float16 half8 __attribute__((ext_vector_type(8)));
typedef _Float16 half4v __attribute__((ext_vector_type(4)));
typedef float f32x16 __attribute__((ext_vector_type(16)));
typedef unsigned short ushort_t;

__device__ inline ushort_t f2h(float f) {
  _Float16 h = (_Float16)f;
  return __builtin_bit_cast(ushort_t, h);
}

// ---- pre-transform weights W[M][K] fp32 -> frag-order fp16 -------------------
// idx = ((cb*(K/16)+kb)*64 + l)*8 + j ; col = cb*32+(l&31); k = kb*16+((l>>5)&1)*8+j
__global__ void k_wconv(const float* __restrict__ W, ushort_t* __restrict__ Bh,
                        int M, int K, int total) {
  int idx = blockIdx.x * 256 + threadIdx.x;
  if (idx >= total) return;
  int j = idx & 7;
  int l = (idx >> 3) & 63;
  int blk = idx >> 9;
  int nKB = K >> 4;
  int cb = blk / nKB, kb = blk - cb * nKB;
  int col = cb * 32 + (l & 31);
  int k = kb * 16 + ((l >> 5) & 1) * 8 + j;
  float v = (col < M) ? W[(size_t)col * K + k] : 0.f;
  Bh[idx] = f2h(v);
}

// ---- fp16 MFMA GEMM (1 MFMA per 16-k block), depth-1 prefetch ----------------
// BM=64, BN=128, 512 thr = 8 waves (2 row x 4 col), per-wave 32x32, BK=BKT.
// AFP16: A is fp16 row-major (staging = pure copy); else fp32 (convert in stage)
// OUTMODE: 0 = f32 to C; 1 = fp16 to C16a; 3 = split fused [Wl;Wr]:
//          cc<128 -> fp16 C16a (bias), cc>=128 -> fp16 C16b (bias2)
template<int ACT, int OUTMODE, int BKT, int AFP16>
__global__ __launch_bounds__(512) void gemm_mfma(const void* __restrict__ Av,
    const ushort_t* __restrict__ Bh,
    const float* __restrict__ bias, const float* __restrict__ bias2,
    float* __restrict__ C, ushort_t* __restrict__ C16a,
    ushort_t* __restrict__ C16b, int N, int M, int K)
{
  constexpr int NKK = BKT / 16;     // 16-k blocks per step
  constexpr int EPT = BKT / 8;      // k-elems per staging thread (4 or 8)
  __shared__ ushort_t Ah[2][2 * NKK * 512];
  const int t = threadIdx.x;
  const int lane = t & 63;
  const int wid = t >> 6;
  const int wr = wid >> 2;
  const int wc = wid & 3;
  const int row0 = blockIdx.x * 64;
  const int col0 = blockIdx.y * 128;
  const int nKB = K >> 4;
  const int nK = K / BKT;

  const int srow = t & 63;
  const int kq = (t >> 6) * EPT;
  const int sbase = ((srow >> 5) * NKK + (kq >> 4)) * 512 +
                    ((srow & 31) + 32 * ((kq >> 3) & 1)) * 8 + (kq & 7);
  const bool arow_ok = (row0 + srow) < N;
  const float*    aptrf = (const float*)Av + (size_t)(row0 + srow) * K + kq;
  const ushort_t* aptrh = (const ushort_t*)Av + (size_t)(row0 + srow) * K + kq;

  const int cb = (col0 >> 5) + wc;

  f32x16 acc = {};
  float vin[EPT];
  half8 hin8 = {};
  half4v hin4 = {};

  auto aload = [&](int ks) {
    if constexpr (AFP16) {
      if constexpr (EPT == 8) {
        half8 z = {};
        hin8 = arow_ok ? *(const half8*)(aptrh + (size_t)ks * BKT) : z;
      } else {
        half4v z = {};
        hin4 = arow_ok ? *(const half4v*)(aptrh + (size_t)ks * BKT) : z;
      }
    } else {
      #pragma unroll
      for (int q = 0; q < EPT; ++q) vin[q] = 0.f;
      if (arow_ok) {
        #pragma unroll
        for (int q4 = 0; q4 < EPT / 4; ++q4) {
          float4 v = *(const float4*)(aptrf + (size_t)ks * BKT + q4 * 4);
          vin[q4 * 4 + 0] = v.x; vin[q4 * 4 + 1] = v.y;
          vin[q4 * 4 + 2] = v.z; vin[q4 * 4 + 3] = v.w;
        }
      }
    }
  };
  auto stage_write = [&](int buf) {
    if constexpr (AFP16) {
      if constexpr (EPT == 8) *(half8*)&Ah[buf][sbase] = hin8;
      else                    *(half4v*)&Ah[buf][sbase] = hin4;
    } else if constexpr (EPT == 8) {
      half8 hv;
      #pragma unroll
      for (int q = 0; q < 8; ++q) hv[q] = (_Float16)vin[q];
      *(half8*)&Ah[buf][sbase] = hv;
    } else {
      half4v hv;
      #pragma unroll
      for (int q = 0; q < 4; ++q) hv[q] = (_Float16)vin[q];
      *(half4v*)&Ah[buf][sbase] = hv;
    }
  };

  aload(0);
  stage_write(0);
  __syncthreads();

  for (int ks = 0; ks < nK; ++ks) {
    const int cur = ks & 1;
    const int nxt = cur ^ 1;
    const bool have_next = (ks + 1 < nK);
    if (have_next) aload(ks + 1);

    #pragma unroll
    for (int kk = 0; kk < NKK; ++kk) {
      const int kbg = ks * NKK + kk;
      const size_t bo = ((size_t)(cb * nKB + kbg) * 64 + lane) * 8;
      half8 bh = *(const half8*)(Bh + bo);
      half8 ah = *(const half8*)&Ah[cur][(wr * NKK + kk) * 512 + lane * 8];
      acc = __builtin_amdgcn_mfma_f32_32x32x16_f16(ah, bh, acc, 0, 0, 0);
    }

    if (have_next) stage_write(nxt);
    __syncthreads();
  }

  // epilogue: D layout col=lane&31, row=(reg&3)+8*(reg>>2)+4*(lane>>5)
  int cc = col0 + wc * 32 + (lane & 31);
  float bv;
  if (OUTMODE == 3) bv = (cc < 128) ? bias[cc] : bias2[cc - 128];
  else              bv = (cc < M) ? bias[cc] : 0.f;
  #pragma unroll
  for (int r = 0; r < 16; ++r) {
    int rr = row0 + wr * 32 + (r & 3) + 8 * (r >> 2) + 4 * (lane >> 5);
    if (rr < N && cc < M) {
      float v = acc[r] + bv;
      if (ACT) v = v > 0.f ? v : (__expf(v) - 1.f);
      if (OUTMODE == 0)      C[(size_t)rr * M + cc] = v;
      else if (OUTMODE == 1) C16a[(size_t)rr * M + cc] = f2h(v);
      else {
        if (cc < 128) C16a[(size_t)rr * 128 + cc] = f2h(v);
        else          C16b[(size_t)rr * 128 + (cc - 128)] = f2h(v);
      }
    }
  }
}

// ---------------- CSR build (dst-sorted edge permutation) ---------------------
__global__ void k_degrank(const int* __restrict__ ei, int* __restrict__ deg,
                          int* __restrict__ rank) {
  int e = blockIdx.x * 256 + threadIdx.x;
  if (e >= NE) return;
  int d = ei[NE + e];
  rank[e] = atomicAdd(&deg[d], 1);
}

__global__ __launch_bounds__(256) void k_scan1(const int* __restrict__ deg,
    int* __restrict__ rowstart, int* __restrict__ blocksum) {
  __shared__ int sm[256];
  int b = blockIdx.x, t = threadIdx.x;
  int i = b * 256 + t;
  int v = (i < NN) ? deg[i] : 0;
  sm[t] = v;
  __syncthreads();
  #pragma unroll
  for (int off = 1; off < 256; off <<= 1) {
    int u = (t >= off) ? sm[t - off] : 0;
    __syncthreads();
    sm[t] += u;
    __syncthreads();
  }
  if (i < NN) rowstart[i + 1] = sm[t];
  if (t == 255) blocksum[b] = sm[255];
}

__global__ __launch_bounds__(256) void k_scan2(int* __restrict__ blocksum, int nb) {
  __shared__ int sm[256];
  int t = threadIdx.x;
  int v = (t < nb) ? blocksum[t] : 0;
  sm[t] = v;
  __syncthreads();
  #pragma unroll
  for (int off = 1; off < 256; off <<= 1) {
    int u = (t >= off) ? sm[t - off] : 0;
    __syncthreads();
    sm[t] += u;
    __syncthreads();
  }
  if (t < nb) blocksum[t] = (t == 0) ? 0 : sm[t - 1];
}

__global__ __launch_bounds__(256) void k_scan3(int* __restrict__ rowstart,
    const int* __restrict__ blocksum) {
  int b = blockIdx.x, t = threadIdx.x;
  int i = b * 256 + t;
  if (i == 0) rowstart[0] = 0;
  if (i < NN) rowstart[i + 1] += blocksum[b];
}

__global__ void k_scatter(const int* __restrict__ ei, const int* __restrict__ rowstart,
                          const int* __restrict__ rank, int* __restrict__ srcp) {
  int e = blockIdx.x * 256 + threadIdx.x;
  if (e >= NE) return;
  int d = ei[NE + e];
  srcp[rowstart[d] + rank[e]] = ei[e];
}

// -------- fused GATv2 edge+node, channel-packed, 8-edge pipelined -------------
// All fp16 I/O: xl, xr gathered/read fp16; output written fp16.
__global__ __launch_bounds__(256) void k_gat(const ushort_t* __restrict__ xl,
    const ushort_t* __restrict__ xr, const int* __restrict__ srcp,
    const int* __restrict__ rowstart, const float* __restrict__ att,
    const float* __restrict__ bias, ushort_t* __restrict__ out)
{
  const int g = threadIdx.x >> 5;
  const int c = threadIdx.x & 31;
  const int n = blockIdx.x * 8 + g;
  const int r0 = rowstart[n], r1 = rowstart[n + 1];
  half4v xrh = *(const half4v*)(xr + (size_t)n * 128 + 4 * c);
  const float4 xrv = make_float4((float)xrh[0], (float)xrh[1],
                                 (float)xrh[2], (float)xrh[3]);
  const float4 atv = *(const float4*)(att + 4 * c);

  float m = -1e30f, ssum = 0.f;
  float a0 = 0.f, a1 = 0.f, a2 = 0.f, a3 = 0.f;

  auto lg = [&](int s, float4& xs) -> float {
    half4v hv = *(const half4v*)(xl + (size_t)s * 128 + 4 * c);
    xs.x = (float)hv[0]; xs.y = (float)hv[1];
    xs.z = (float)hv[2]; xs.w = (float)hv[3];
    float u0 = xs.x + xrv.x; u0 = fmaxf(u0, 0.2f * u0);
    float u1 = xs.y + xrv.y; u1 = fmaxf(u1, 0.2f * u1);
    float u2 = xs.z + xrv.z; u2 = fmaxf(u2, 0.2f * u2);
    float u3 = xs.w + xrv.w; u3 = fmaxf(u3, 0.2f * u3);
    float l = u0 * atv.x + u1 * atv.y + u2 * atv.z + u3 * atv.w;
    l += __shfl_xor(l, 1);
    l += __shfl_xor(l, 2);
    l += __shfl_xor(l, 4);
    return l;
  };

  int j = r0;
  for (; j + 8 <= r1; j += 8) {
    int s0 = srcp[j],     s1 = srcp[j + 1], s2 = srcp[j + 2], s3 = srcp[j + 3];
    int s4 = srcp[j + 4], s5 = srcp[j + 5], s6 = srcp[j + 6], s7 = srcp[j + 7];
    float4 x0, x1, x2, x3, x4, x5, x6, x7;
    float l0 = lg(s0, x0), l1 = lg(s1, x1), l2 = lg(s2, x2), l3 = lg(s3, x3);
    float l4 = lg(s4, x4), l5 = lg(s5, x5), l6 = lg(s6, x6), l7 = lg(s7, x7);
    float mloc = fmaxf(fmaxf(fmaxf(l0, l1), fmaxf(l2, l3)),
                       fmaxf(fmaxf(l4, l5), fmaxf(l6, l7)));
    float mn = fmaxf(m, mloc);
    float sc = __expf(m - mn);
    float p0 = __expf(l0 - mn), p1 = __expf(l1 - mn);
    float p2 = __expf(l2 - mn), p3 = __expf(l3 - mn);
    float p4 = __expf(l4 - mn), p5 = __expf(l5 - mn);
    float p6 = __expf(l6 - mn), p7 = __expf(l7 - mn);
    ssum = ssum * sc + (((p0 + p1) + (p2 + p3)) + ((p4 + p5) + (p6 + p7)));
    a0 = a0 * sc + (((p0 * x0.x + p1 * x1.x) + (p2 * x2.x + p3 * x3.x)) +
                    ((p4 * x4.x + p5 * x5.x) + (p6 * x6.x + p7 * x7.x)));
    a1 = a1 * sc + (((p0 * x0.y + p1 * x1.y) + (p2 * x2.y + p3 * x3.y)) +
                    ((p4 * x4.y + p5 * x5.y) + (p6 * x6.y + p7 * x7.y)));
    a2 = a2 * sc + (((p0 * x0.z + p1 * x1.z) + (p2 * x2.z + p3 * x3.z)) +
                    ((p4 * x4.z + p5 * x5.z) + (p6 * x6.z + p7 * x7.z)));
    a3 = a3 * sc + (((p0 * x0.w + p1 * x1.w) + (p2 * x2.w + p3 * x3.w)) +
                    ((p4 * x4.w + p5 * x5.w) + (p6 * x6.w + p7 * x7.w)));
    m = mn;
  }
  for (; j + 4 <= r1; j += 4) {
    int s0 = srcp[j], s1 = srcp[j + 1], s2 = srcp[j + 2], s3 = srcp[j + 3];
    float4 x0, x1, x2, x3;
    float l0 = lg(s0, x0), l1 = lg(s1, x1), l2 = lg(s2, x2), l3 = lg(s3, x3);
    float mloc = fmaxf(fmaxf(l0, l1), fmaxf(l2, l3));
    float mn = fmaxf(m, mloc);
    float sc = __expf(m - mn);
    float p0 = __expf(l0 - mn), p1 = __expf(l1 - mn);
    float p2 = __expf(l2 - mn), p3 = __expf(l3 - mn);
    ssum = ssum * sc + ((p0 + p1) + (p2 + p3));
    a0 = a0 * sc + (p0 * x0.x + p1 * x1.x) + (p2 * x2.x + p3 * x3.x);
    a1 = a1 * sc + (p0 * x0.y + p1 * x1.y) + (p2 * x2.y + p3 * x3.y);
    a2 = a2 * sc + (p0 * x0.z + p1 * x1.z) + (p2 * x2.z + p3 * x3.z);
    a3 = a3 * sc + (p0 * x0.w + p1 * x1.w) + (p2 * x2.w + p3 * x3.w);
    m = mn;
  }
  for (; j < r1; ++j) {
    float4 xs;
    float l = lg(srcp[j], xs);
    float mn = fmaxf(m, l);
    float sc = __expf(m - mn);
    float p = __expf(l - mn);
    ssum = ssum * sc + p;
    a0 = a0 * sc + p * xs.x;
    a1 = a1 * sc + p * xs.y;
    a2 = a2 * sc + p * xs.z;
    a3 = a3 * sc + p * xs.w;
    m = mn;
  }

  const float4 bv = *(const float4*)(bias + 4 * c);
  float rinv = 1.f / (ssum + 1e-16f);
  float o0 = a0 * rinv + bv.x;
  float o1 = a1 * rinv + bv.y;
  float o2 = a2 * rinv + bv.z;
  float o3 = a3 * rinv + bv.w;
  o0 = o0 > 0.f ? o0 : (__expf(o0) - 1.f);
  o1 = o1 > 0.f ? o1 : (__expf(o1) - 1.f);
  o2 = o2 > 0.f ? o2 : (__expf(o2) - 1.f);
  o3 = o3 > 0.f ? o3 : (__expf(o3) - 1.f);
  half4v ov;
  ov[0] = (_Float16)o0; ov[1] = (_Float16)o1;
  ov[2] = (_Float16)o2; ov[3] = (_Float16)o3;
  *(half4v*)(out + (size_t)n * 128 + 4 * c) = ov;
}

__global__ void k_report_ws(float* out, int out_size, float wsz) {
  int i = blockIdx.x * 256 + threadIdx.x;
  if (i < out_size) out[i] = (i == 0) ? wsz : 0.f;
}

// -----------------------------------------------------------------------------
extern "C" void kernel_launch(void* const* d_in, const int* in_sizes, int n_in,
                              void* d_out, int out_size, void* d_ws, size_t ws_size,
                              hipStream_t stream)
{
  const float* x    = (const float*)d_in[0];
  const int*   ei   = (const int*)d_in[1];     // int32 [2,E] row-major
  const float* Wp   = (const float*)d_in[2];  const float* bp    = (const float*)d_in[3];
  const float* Wl1  = (const float*)d_in[4];  const float* bl1   = (const float*)d_in[5];
  const float* Wr1  = (const float*)d_in[6];  const float* br1   = (const float*)d_in[7];
  const float* att1 = (const float*)d_in[8];  const float* bias1 = (const float*)d_in[9];
  const float* Wl2  = (const float*)d_in[10]; const float* bl2   = (const float*)d_in[11];
  const float* Wr2  = (const float*)d_in[12]; const float* br2   = (const float*)d_in[13];
  const float* att2 = (const float*)d_in[14]; const float* bias2 = (const float*)d_in[15];
  const float* W1   = (const float*)d_in[16]; const float* b1    = (const float*)d_in[17];
  const float* W2   = (const float*)d_in[18]; const float* b2    = (const float*)d_in[19];
  float* out = (float*)d_out;

  constexpr size_t NEED = 122300000;
  if (ws_size < NEED) {
    k_report_ws<<<(out_size + 255) / 256, 256, 0, stream>>>(out, out_size, (float)ws_size);
    return;
  }
  char* ws = (char*)d_ws;
  ushort_t* h0h   = (ushort_t*)(ws + 0);          // 50000*256 fp16 (25.6 MB)
  ushort_t* h1h   = h0h;                          // 50000*128 fp16 (reuse)
  ushort_t* h2h   = (ushort_t*)(ws + 25600000);   // 50000*128 fp16
  ushort_t* xlh   = (ushort_t*)(ws + 51200000);   // 50000*128 fp16
  ushort_t* xrh   = (ushort_t*)(ws + 76800000);   // 50000*128 fp16
  ushort_t* h3h   = (ushort_t*)(ws + 102400000);  // 50000*32 fp16
  ushort_t* wb    = (ushort_t*)(ws + 108800000);  // fp16 weight frag buffers
  int*      srcp  = (int*)(ws + 115200000);
  int*      rank  = (int*)(ws + 118400000);
  int*      deg   = (int*)(ws + 121600000);
  int*      rowst = (int*)(ws + 122000000);
  int*      bsum  = (int*)(ws + 122250000);

  // weight carve (element offsets in halves)
  ushort_t* Wph  = wb;             // 131072  (256x512)
  ushort_t* WB1h = wb + 131072;    // 65536   ([Wl1;Wr1])
  ushort_t* WB2h = wb + 196608;    // 32768   ([Wl2;Wr2])
  ushort_t* W1h  = wb + 229376;    // 4096
  ushort_t* W2h  = wb + 233472;    // 1024

  hipMemsetAsync(deg, 0, NN * sizeof(int), stream);

  k_wconv<<<(131072+255)/256, 256, 0, stream>>>(Wp,  Wph,          256, 512, 131072);
  k_wconv<<<(32768+255)/256,  256, 0, stream>>>(Wl1, WB1h,         128, 256, 32768);
  k_wconv<<<(32768+255)/256,  256, 0, stream>>>(Wr1, WB1h + 32768, 128, 256, 32768);
  k_wconv<<<(16384+255)/256,  256, 0, stream>>>(Wl2, WB2h,         128, 128, 16384);
  k_wconv<<<(16384+255)/256,  256, 0, stream>>>(Wr2, WB2h + 16384, 128, 128, 16384);
  k_wconv<<<(4096+255)/256,   256, 0, stream>>>(W1,  W1h,          32,  128, 4096);
  k_wconv<<<(1024+255)/256,   256, 0, stream>>>(W2,  W2h,          10,  32,  1024);

  constexpr int NB = (NN + 255) / 256;
  k_degrank<<<(NE+255)/256, 256, 0, stream>>>(ei, deg, rank);
  k_scan1  <<<NB, 256, 0, stream>>>(deg, rowst, bsum);
  k_scan2  <<<1, 256, 0, stream>>>(bsum, NB);
  k_scan3  <<<NB, 256, 0, stream>>>(rowst, bsum);
  k_scatter<<<(NE+255)/256, 256, 0, stream>>>(ei, rowst, rank, srcp);

  constexpr int GX = (NN + 63) / 64;  // 782

  // projection: h0 = elu(x @ Wp^T + bp) -> fp16, M=256, K=512 (A fp32)
  gemm_mfma<1,1,64,0><<<dim3(GX, 2), 512, 0, stream>>>(
      x, Wph, bp, nullptr, nullptr, h0h, nullptr, NN, 256, 512);

  // GAT layer 1: fused [xl|xr] = h0 @ [Wl1;Wr1]^T, M=256, K=256 (A fp16)
  gemm_mfma<0,3,64,1><<<dim3(GX, 2), 512, 0, stream>>>(
      h0h, WB1h, bl1, br1, nullptr, xlh, xrh, NN, 256, 256);
  k_gat<<<NN/8, 256, 0, stream>>>(xlh, xrh, srcp, rowst, att1, bias1, h1h);

  // GAT layer 2: fused, M=256, K=128 (A fp16)
  gemm_mfma<0,3,64,1><<<dim3(GX, 2), 512, 0, stream>>>(
      h1h, WB2h, bl2, br2, nullptr, xlh, xrh, NN, 256, 128);
  k_gat<<<NN/8, 256, 0, stream>>>(xlh, xrh, srcp, rowst, att2, bias2, h2h);

  // head MLP: h3 = elu(h2 @ W1^T + b1) fp16; out = h3 @ W2^T + b2 f32
  gemm_mfma<1,1,64,1><<<dim3(GX, 1), 512, 0, stream>>>(
      h2h, W1h, b1, nullptr, nullptr, h3h, nullptr, NN, 32, 128);
  gemm_mfma<0,0,32,1><<<dim3(GX, 1), 512, 0, stream>>>(
      h3h, W2h, b2, nullptr, out, nullptr, nullptr, NN, 10, 32);
}

// Round 15
// 272.033 us; speedup vs baseline: 1.4973x; 1.0455x over previous
//
#include <hip/hip_runtime.h>
#include <cstdint>
#include <cstddef>

constexpr int NN = 50000;
constexpr int NE = 800000;

typedef _Float16 half8 __attribute__((ext_vector_type(8)));
typedef _Float16 half4v __attribute__((ext_vector_type(4)));
typedef _Float16 half2v __attribute__((ext_vector_type(2)));
typedef float f32x16 __attribute__((ext_vector_type(16)));
typedef unsigned short ushort_t;

__device__ inline ushort_t f2h(float f) {
  _Float16 h = (_Float16)f;
  return __builtin_bit_cast(ushort_t, h);
}

#if __has_builtin(__builtin_amdgcn_fdot2)
__device__ inline float fdot2(half2v a, half2v b, float c) {
  return __builtin_amdgcn_fdot2(a, b, c, false);
}
#else
__device__ inline float fdot2(half2v a, half2v b, float c) {
  return c + (float)a[0] * (float)b[0] + (float)a[1] * (float)b[1];
}
#endif

// ---- pre-transform weights W[M][K] fp32 -> frag-order fp16 -------------------
// idx = ((cb*(K/16)+kb)*64 + l)*8 + j ; col = cb*32+(l&31); k = kb*16+((l>>5)&1)*8+j
__global__ void k_wconv(const float* __restrict__ W, ushort_t* __restrict__ Bh,
                        int M, int K, int total) {
  int idx = blockIdx.x * 256 + threadIdx.x;
  if (idx >= total) return;
  int j = idx & 7;
  int l = (idx >> 3) & 63;
  int blk = idx >> 9;
  int nKB = K >> 4;
  int cb = blk / nKB, kb = blk - cb * nKB;
  int col = cb * 32 + (l & 31);
  int k = kb * 16 + ((l >> 5) & 1) * 8 + j;
  float v = (col < M) ? W[(size_t)col * K + k] : 0.f;
  Bh[idx] = f2h(v);
}

// ---- fp16 MFMA GEMM, depth-1 prefetch, NCB col-blocks per wave ---------------
// BM=64, BN=128*NCB, 512 thr = 8 waves (2 row x 4 col), per-wave 32 x 32*NCB.
// NCB=2: single column pass over M=256 -> A staged ONCE (key lever).
// AFP16: A fp16 row-major (stage = copy) vs fp32 (convert in stage).
// OUTMODE: 0 = f32 C; 1 = fp16 C16a; 3 = split fused [Wl;Wr]:
//          cc<128 -> C16a (bias), cc>=128 -> C16b (bias2), both stride 128.
template<int ACT, int OUTMODE, int BKT, int AFP16, int NCB>
__global__ __launch_bounds__(512) void gemm_mfma(const void* __restrict__ Av,
    const ushort_t* __restrict__ Bh,
    const float* __restrict__ bias, const float* __restrict__ bias2,
    float* __restrict__ C, ushort_t* __restrict__ C16a,
    ushort_t* __restrict__ C16b, int N, int M, int K)
{
  constexpr int NKK = BKT / 16;     // 16-k blocks per step
  constexpr int EPT = BKT / 8;      // k-elems per staging thread
  __shared__ ushort_t Ah[2][2 * NKK * 512];
  const int t = threadIdx.x;
  const int lane = t & 63;
  const int wid = t >> 6;
  const int wr = wid >> 2;
  const int wc = wid & 3;
  const int row0 = blockIdx.x * 64;
  const int col0 = blockIdx.y * (128 * NCB);
  const int nKB = K >> 4;
  const int nK = K / BKT;

  const int srow = t & 63;
  const int kq = (t >> 6) * EPT;
  const int sbase = ((srow >> 5) * NKK + (kq >> 4)) * 512 +
                    ((srow & 31) + 32 * ((kq >> 3) & 1)) * 8 + (kq & 7);
  const bool arow_ok = (row0 + srow) < N;
  const float*    aptrf = (const float*)Av + (size_t)(row0 + srow) * K + kq;
  const ushort_t* aptrh = (const ushort_t*)Av + (size_t)(row0 + srow) * K + kq;

  const int cb0 = (col0 >> 5) + wc * NCB;

  f32x16 acc0 = {}, acc1 = {};
  float vin[EPT];
  half8 hin8 = {};
  half4v hin4 = {};

  auto aload = [&](int ks) {
    if constexpr (AFP16) {
      if constexpr (EPT == 8) {
        half8 z = {};
        hin8 = arow_ok ? *(const half8*)(aptrh + (size_t)ks * BKT) : z;
      } else {
        half4v z = {};
        hin4 = arow_ok ? *(const half4v*)(aptrh + (size_t)ks * BKT) : z;
      }
    } else {
      #pragma unroll
      for (int q = 0; q < EPT; ++q) vin[q] = 0.f;
      if (arow_ok) {
        #pragma unroll
        for (int q4 = 0; q4 < EPT / 4; ++q4) {
          float4 v = *(const float4*)(aptrf + (size_t)ks * BKT + q4 * 4);
          vin[q4 * 4 + 0] = v.x; vin[q4 * 4 + 1] = v.y;
          vin[q4 * 4 + 2] = v.z; vin[q4 * 4 + 3] = v.w;
        }
      }
    }
  };
  auto stage_write = [&](int buf) {
    if constexpr (AFP16) {
      if constexpr (EPT == 8) *(half8*)&Ah[buf][sbase] = hin8;
      else                    *(half4v*)&Ah[buf][sbase] = hin4;
    } else if constexpr (EPT == 8) {
      half8 hv;
      #pragma unroll
      for (int q = 0; q < 8; ++q) hv[q] = (_Float16)vin[q];
      *(half8*)&Ah[buf][sbase] = hv;
    } else {
      half4v hv;
      #pragma unroll
      for (int q = 0; q < 4; ++q) hv[q] = (_Float16)vin[q];
      *(half4v*)&Ah[buf][sbase] = hv;
    }
  };

  aload(0);
  stage_write(0);
  __syncthreads();

  for (int ks = 0; ks < nK; ++ks) {
    const int cur = ks & 1;
    const int nxt = cur ^ 1;
    const bool have_next = (ks + 1 < nK);
    if (have_next) aload(ks + 1);

    #pragma unroll
    for (int kk = 0; kk < NKK; ++kk) {
      const int kbg = ks * NKK + kk;
      half8 ah = *(const half8*)&Ah[cur][(wr * NKK + kk) * 512 + lane * 8];
      const size_t bo0 = ((size_t)(cb0 * nKB + kbg) * 64 + lane) * 8;
      half8 bh0 = *(const half8*)(Bh + bo0);
      acc0 = __builtin_amdgcn_mfma_f32_32x32x16_f16(ah, bh0, acc0, 0, 0, 0);
      if constexpr (NCB == 2) {
        const size_t bo1 = ((size_t)((cb0 + 1) * nKB + kbg) * 64 + lane) * 8;
        half8 bh1 = *(const half8*)(Bh + bo1);
        acc1 = __builtin_amdgcn_mfma_f32_32x32x16_f16(ah, bh1, acc1, 0, 0, 0);
      }
    }

    if (have_next) stage_write(nxt);
    __syncthreads();
  }

  // epilogue: D layout col=lane&31, row=(reg&3)+8*(reg>>2)+4*(lane>>5)
  auto epi = [&](const f32x16& acc, int cb) {
    int cc = cb * 32 + (lane & 31);
    float bv;
    if constexpr (OUTMODE == 3) bv = (cc < 128) ? bias[cc] : bias2[cc - 128];
    else                        bv = (cc < M) ? bias[cc] : 0.f;
    #pragma unroll
    for (int r = 0; r < 16; ++r) {
      int rr = row0 + wr * 32 + (r & 3) + 8 * (r >> 2) + 4 * (lane >> 5);
      if (rr < N && cc < M) {
        float v = acc[r] + bv;
        if (ACT) v = v > 0.f ? v : (__expf(v) - 1.f);
        if constexpr (OUTMODE == 0)      C[(size_t)rr * M + cc] = v;
        else if constexpr (OUTMODE == 1) C16a[(size_t)rr * M + cc] = f2h(v);
        else {
          if (cc < 128) C16a[(size_t)rr * 128 + cc] = f2h(v);
          else          C16b[(size_t)rr * 128 + (cc - 128)] = f2h(v);
        }
      }
    }
  };
  epi(acc0, cb0);
  if constexpr (NCB == 2) epi(acc1, cb0 + 1);
}

// ---------------- CSR build (dst-sorted edge permutation) ---------------------
__global__ void k_degrank(const int* __restrict__ ei, int* __restrict__ deg,
                          int* __restrict__ rank) {
  int e = blockIdx.x * 256 + threadIdx.x;
  if (e >= NE) return;
  int d = ei[NE + e];
  rank[e] = atomicAdd(&deg[d], 1);
}

__global__ __launch_bounds__(256) void k_scan1(const int* __restrict__ deg,
    int* __restrict__ rowstart, int* __restrict__ blocksum) {
  __shared__ int sm[256];
  int b = blockIdx.x, t = threadIdx.x;
  int i = b * 256 + t;
  int v = (i < NN) ? deg[i] : 0;
  sm[t] = v;
  __syncthreads();
  #pragma unroll
  for (int off = 1; off < 256; off <<= 1) {
    int u = (t >= off) ? sm[t - off] : 0;
    __syncthreads();
    sm[t] += u;
    __syncthreads();
  }
  if (i < NN) rowstart[i + 1] = sm[t];
  if (t == 255) blocksum[b] = sm[255];
}

__global__ __launch_bounds__(256) void k_scan2(int* __restrict__ blocksum, int nb) {
  __shared__ int sm[256];
  int t = threadIdx.x;
  int v = (t < nb) ? blocksum[t] : 0;
  sm[t] = v;
  __syncthreads();
  #pragma unroll
  for (int off = 1; off < 256; off <<= 1) {
    int u = (t >= off) ? sm[t - off] : 0;
    __syncthreads();
    sm[t] += u;
    __syncthreads();
  }
  if (t < nb) blocksum[t] = (t == 0) ? 0 : sm[t - 1];
}

__global__ __launch_bounds__(256) void k_scan3(int* __restrict__ rowstart,
    const int* __restrict__ blocksum) {
  int b = blockIdx.x, t = threadIdx.x;
  int i = b * 256 + t;
  if (i == 0) rowstart[0] = 0;
  if (i < NN) rowstart[i + 1] += blocksum[b];
}

__global__ void k_scatter(const int* __restrict__ ei, const int* __restrict__ rowstart,
                          const int* __restrict__ rank, int* __restrict__ srcp) {
  int e = blockIdx.x * 256 + threadIdx.x;
  if (e >= NE) return;
  int d = ei[NE + e];
  srcp[rowstart[d] + rank[e]] = ei[e];
}

// -------- fused GATv2 edge+node, channel-packed, 8-edge pipelined -------------
// Packed-fp16 logit: lrelu(xs+xr) via v_pk_* + v_dot2_f32_f16 att-dot.
__global__ __launch_bounds__(256) void k_gat(const ushort_t* __restrict__ xl,
    const ushort_t* __restrict__ xr, const int* __restrict__ srcp,
    const int* __restrict__ rowstart, const float* __restrict__ att,
    const float* __restrict__ bias, ushort_t* __restrict__ out)
{
  const int g = threadIdx.x >> 5;
  const int c = threadIdx.x & 31;
  const int n = blockIdx.x * 8 + g;
  const int r0 = rowstart[n], r1 = rowstart[n + 1];
  half4v xrh = *(const half4v*)(xr + (size_t)n * 128 + 4 * c);
  const half2v xr01 = {xrh[0], xrh[1]};
  const half2v xr23 = {xrh[2], xrh[3]};
  const float4 atv = *(const float4*)(att + 4 * c);
  const half2v at01 = {(_Float16)atv.x, (_Float16)atv.y};
  const half2v at23 = {(_Float16)atv.z, (_Float16)atv.w};
  const half2v k02 = {(_Float16)0.2f, (_Float16)0.2f};

  float m = -1e30f, ssum = 0.f;
  float a0 = 0.f, a1 = 0.f, a2 = 0.f, a3 = 0.f;

  auto lg = [&](int s, float4& xs) -> float {
    half4v hv = *(const half4v*)(xl + (size_t)s * 128 + 4 * c);
    xs.x = (float)hv[0]; xs.y = (float)hv[1];
    xs.z = (float)hv[2]; xs.w = (float)hv[3];
    half2v u01 = half2v{hv[0], hv[1]} + xr01;
    half2v u23 = half2v{hv[2], hv[3]} + xr23;
    u01 = __builtin_elementwise_max(u01, u01 * k02);
    u23 = __builtin_elementwise_max(u23, u23 * k02);
    float l = fdot2(u01, at01, fdot2(u23, at23, 0.f));
    l += __shfl_xor(l, 1);
    l += __shfl_xor(l, 2);
    l += __shfl_xor(l, 4);
    return l;
  };

  int j = r0;
  for (; j + 8 <= r1; j += 8) {
    int s0 = srcp[j],     s1 = srcp[j + 1], s2 = srcp[j + 2], s3 = srcp[j + 3];
    int s4 = srcp[j + 4], s5 = srcp[j + 5], s6 = srcp[j + 6], s7 = srcp[j + 7];
    float4 x0, x1, x2, x3, x4, x5, x6, x7;
    float l0 = lg(s0, x0), l1 = lg(s1, x1), l2 = lg(s2, x2), l3 = lg(s3, x3);
    float l4 = lg(s4, x4), l5 = lg(s5, x5), l6 = lg(s6, x6), l7 = lg(s7, x7);
    float mloc = fmaxf(fmaxf(fmaxf(l0, l1), fmaxf(l2, l3)),
                       fmaxf(fmaxf(l4, l5), fmaxf(l6, l7)));
    float mn = fmaxf(m, mloc);
    float sc = __expf(m - mn);
    float p0 = __expf(l0 - mn), p1 = __expf(l1 - mn);
    float p2 = __expf(l2 - mn), p3 = __expf(l3 - mn);
    float p4 = __expf(l4 - mn), p5 = __expf(l5 - mn);
    float p6 = __expf(l6 - mn), p7 = __expf(l7 - mn);
    ssum = ssum * sc + (((p0 + p1) + (p2 + p3)) + ((p4 + p5) + (p6 + p7)));
    a0 = a0 * sc + (((p0 * x0.x + p1 * x1.x) + (p2 * x2.x + p3 * x3.x)) +
                    ((p4 * x4.x + p5 * x5.x) + (p6 * x6.x + p7 * x7.x)));
    a1 = a1 * sc + (((p0 * x0.y + p1 * x1.y) + (p2 * x2.y + p3 * x3.y)) +
                    ((p4 * x4.y + p5 * x5.y) + (p6 * x6.y + p7 * x7.y)));
    a2 = a2 * sc + (((p0 * x0.z + p1 * x1.z) + (p2 * x2.z + p3 * x3.z)) +
                    ((p4 * x4.z + p5 * x5.z) + (p6 * x6.z + p7 * x7.z)));
    a3 = a3 * sc + (((p0 * x0.w + p1 * x1.w) + (p2 * x2.w + p3 * x3.w)) +
                    ((p4 * x4.w + p5 * x5.w) + (p6 * x6.w + p7 * x7.w)));
    m = mn;
  }
  for (; j + 4 <= r1; j += 4) {
    int s0 = srcp[j], s1 = srcp[j + 1], s2 = srcp[j + 2], s3 = srcp[j + 3];
    float4 x0, x1, x2, x3;
    float l0 = lg(s0, x0), l1 = lg(s1, x1), l2 = lg(s2, x2), l3 = lg(s3, x3);
    float mloc = fmaxf(fmaxf(l0, l1), fmaxf(l2, l3));
    float mn = fmaxf(m, mloc);
    float sc = __expf(m - mn);
    float p0 = __expf(l0 - mn), p1 = __expf(l1 - mn);
    float p2 = __expf(l2 - mn), p3 = __expf(l3 - mn);
    ssum = ssum * sc + ((p0 + p1) + (p2 + p3));
    a0 = a0 * sc + (p0 * x0.x + p1 * x1.x) + (p2 * x2.x + p3 * x3.x);
    a1 = a1 * sc + (p0 * x0.y + p1 * x1.y) + (p2 * x2.y + p3 * x3.y);
    a2 = a2 * sc + (p0 * x0.z + p1 * x1.z) + (p2 * x2.z + p3 * x3.z);
    a3 = a3 * sc + (p0 * x0.w + p1 * x1.w) + (p2 * x2.w + p3 * x3.w);
    m = mn;
  }
  for (; j < r1; ++j) {
    float4 xs;
    float l = lg(srcp[j], xs);
    float mn = fmaxf(m, l);
    float sc = __expf(m - mn);
    float p = __expf(l - mn);
    ssum = ssum * sc + p;
    a0 = a0 * sc + p * xs.x;
    a1 = a1 * sc + p * xs.y;
    a2 = a2 * sc + p * xs.z;
    a3 = a3 * sc + p * xs.w;
    m = mn;
  }

  const float4 bv = *(const float4*)(bias + 4 * c);
  float rinv = 1.f / (ssum + 1e-16f);
  float o0 = a0 * rinv + bv.x;
  float o1 = a1 * rinv + bv.y;
  float o2 = a2 * rinv + bv.z;
  float o3 = a3 * rinv + bv.w;
  o0 = o0 > 0.f ? o0 : (__expf(o0) - 1.f);
  o1 = o1 > 0.f ? o1 : (__expf(o1) - 1.f);
  o2 = o2 > 0.f ? o2 : (__expf(o2) - 1.f);
  o3 = o3 > 0.f ? o3 : (__expf(o3) - 1.f);
  half4v ov;
  ov[0] = (_Float16)o0; ov[1] = (_Float16)o1;
  ov[2] = (_Float16)o2; ov[3] = (_Float16)o3;
  *(half4v*)(out + (size_t)n * 128 + 4 * c) = ov;
}

__global__ void k_report_ws(float* out, int out_size, float wsz) {
  int i = blockIdx.x * 256 + threadIdx.x;
  if (i < out_size) out[i] = (i == 0) ? wsz : 0.f;
}

// -----------------------------------------------------------------------------
extern "C" void kernel_launch(void* const* d_in, const int* in_sizes, int n_in,
                              void* d_out, int out_size, void* d_ws, size_t ws_size,
                              hipStream_t stream)
{
  const float* x    = (const float*)d_in[0];
  const int*   ei   = (const int*)d_in[1];     // int32 [2,E] row-major
  const float* Wp   = (const float*)d_in[2];  const float* bp    = (const float*)d_in[3];
  const float* Wl1  = (const float*)d_in[4];  const float* bl1   = (const float*)d_in[5];
  const float* Wr1  = (const float*)d_in[6];  const float* br1   = (const float*)d_in[7];
  const float* att1 = (const float*)d_in[8];  const float* bias1 = (const float*)d_in[9];
  const float* Wl2  = (const float*)d_in[10]; const float* bl2   = (const float*)d_in[11];
  const float* Wr2  = (const float*)d_in[12]; const float* br2   = (const float*)d_in[13];
  const float* att2 = (const float*)d_in[14]; const float* bias2 = (const float*)d_in[15];
  const float* W1   = (const float*)d_in[16]; const float* b1    = (const float*)d_in[17];
  const float* W2   = (const float*)d_in[18]; const float* b2    = (const float*)d_in[19];
  float* out = (float*)d_out;

  constexpr size_t NEED = 122300000;
  if (ws_size < NEED) {
    k_report_ws<<<(out_size + 255) / 256, 256, 0, stream>>>(out, out_size, (float)ws_size);
    return;
  }
  char* ws = (char*)d_ws;
  ushort_t* h0h   = (ushort_t*)(ws + 0);          // 50000*256 fp16
  ushort_t* h1h   = h0h;                          // reuse
  ushort_t* h2h   = (ushort_t*)(ws + 25600000);
  ushort_t* xlh   = (ushort_t*)(ws + 51200000);
  ushort_t* xrh   = (ushort_t*)(ws + 76800000);
  ushort_t* h3h   = (ushort_t*)(ws + 102400000);
  ushort_t* wb    = (ushort_t*)(ws + 108800000);
  int*      srcp  = (int*)(ws + 115200000);
  int*      rank  = (int*)(ws + 118400000);
  int*      deg   = (int*)(ws + 121600000);
  int*      rowst = (int*)(ws + 122000000);
  int*      bsum  = (int*)(ws + 122250000);

  ushort_t* Wph  = wb;             // 131072
  ushort_t* WB1h = wb + 131072;    // 65536
  ushort_t* WB2h = wb + 196608;    // 32768
  ushort_t* W1h  = wb + 229376;    // 4096
  ushort_t* W2h  = wb + 233472;    // 1024

  hipMemsetAsync(deg, 0, NN * sizeof(int), stream);

  k_wconv<<<(131072+255)/256, 256, 0, stream>>>(Wp,  Wph,          256, 512, 131072);
  k_wconv<<<(32768+255)/256,  256, 0, stream>>>(Wl1, WB1h,         128, 256, 32768);
  k_wconv<<<(32768+255)/256,  256, 0, stream>>>(Wr1, WB1h + 32768, 128, 256, 32768);
  k_wconv<<<(16384+255)/256,  256, 0, stream>>>(Wl2, WB2h,         128, 128, 16384);
  k_wconv<<<(16384+255)/256,  256, 0, stream>>>(Wr2, WB2h + 16384, 128, 128, 16384);
  k_wconv<<<(4096+255)/256,   256, 0, stream>>>(W1,  W1h,          32,  128, 4096);
  k_wconv<<<(1024+255)/256,   256, 0, stream>>>(W2,  W2h,          10,  32,  1024);

  constexpr int NB = (NN + 255) / 256;
  k_degrank<<<(NE+255)/256, 256, 0, stream>>>(ei, deg, rank);
  k_scan1  <<<NB, 256, 0, stream>>>(deg, rowst, bsum);
  k_scan2  <<<1, 256, 0, stream>>>(bsum, NB);
  k_scan3  <<<NB, 256, 0, stream>>>(rowst, bsum);
  k_scatter<<<(NE+255)/256, 256, 0, stream>>>(ei, rowst, rank, srcp);

  constexpr int GX = (NN + 63) / 64;  // 782

  // projection: h0 = elu(x @ Wp^T + bp) -> fp16, M=256, K=512, single col pass
  gemm_mfma<1,1,64,0,2><<<dim3(GX, 1), 512, 0, stream>>>(
      x, Wph, bp, nullptr, nullptr, h0h, nullptr, NN, 256, 512);

  // GAT layer 1: fused [xl|xr] = h0 @ [Wl1;Wr1]^T, M=256, K=256, single pass
  gemm_mfma<0,3,64,1,2><<<dim3(GX, 1), 512, 0, stream>>>(
      h0h, WB1h, bl1, br1, nullptr, xlh, xrh, NN, 256, 256);
  k_gat<<<NN/8, 256, 0, stream>>>(xlh, xrh, srcp, rowst, att1, bias1, h1h);

  // GAT layer 2: fused, M=256, K=128, single pass
  gemm_mfma<0,3,64,1,2><<<dim3(GX, 1), 512, 0, stream>>>(
      h1h, WB2h, bl2, br2, nullptr, xlh, xrh, NN, 256, 128);
  k_gat<<<NN/8, 256, 0, stream>>>(xlh, xrh, srcp, rowst, att2, bias2, h2h);

  // head MLP: h3 = elu(h2 @ W1^T + b1) fp16; out = h3 @ W2^T + b2 f32
  gemm_mfma<1,1,64,1,1><<<dim3(GX, 1), 512, 0, stream>>>(
      h2h, W1h, b1, nullptr, nullptr, h3h, nullptr, NN, 32, 128);
  gemm_mfma<0,0,32,1,1><<<dim3(GX, 1), 512, 0, stream>>>(
      h3h, W2h, b2, nullptr, out, nullptr, nullptr, NN, 10, 32);
}

// Round 17
// 265.359 us; speedup vs baseline: 1.5350x; 1.0252x over previous
//
#include <hip/hip_runtime.h>
#include <cstdint>
#include <cstddef>

constexpr int NN = 50000;
constexpr int NE = 800000;

typedef _Float16 half8 __attribute__((ext_vector_type(8)));
typedef _Float16 half4v __attribute__((ext_vector_type(4)));
typedef _Float16 half2v __attribute__((ext_vector_type(2)));
typedef float f32x16 __attribute__((ext_vector_type(16)));
typedef unsigned short ushort_t;

__device__ inline ushort_t f2h(float f) {
  _Float16 h = (_Float16)f;
  return __builtin_bit_cast(ushort_t, h);
}

#if __has_builtin(__builtin_amdgcn_fdot2)
__device__ inline float fdot2(half2v a, half2v b, float c) {
  return __builtin_amdgcn_fdot2(a, b, c, false);
}
#else
__device__ inline float fdot2(half2v a, half2v b, float c) {
  return c + (float)a[0] * (float)b[0] + (float)a[1] * (float)b[1];
}
#endif

// ---- pre-transform weights W[M][K] fp32 -> frag-order fp16 -------------------
// idx = ((cb*(K/16)+kb)*64 + l)*8 + j ; col = cb*32+(l&31); k = kb*16+((l>>5)&1)*8+j
__global__ void k_wconv(const float* __restrict__ W, ushort_t* __restrict__ Bh,
                        int M, int K, int total) {
  int idx = blockIdx.x * 256 + threadIdx.x;
  if (idx >= total) return;
  int j = idx & 7;
  int l = (idx >> 3) & 63;
  int blk = idx >> 9;
  int nKB = K >> 4;
  int cb = blk / nKB, kb = blk - cb * nKB;
  int col = cb * 32 + (l & 31);
  int k = kb * 16 + ((l >> 5) & 1) * 8 + j;
  float v = (col < M) ? W[(size_t)col * K + k] : 0.f;
  Bh[idx] = f2h(v);
}

// ---- fp16 MFMA GEMM, depth-1 prefetch, NCB col-blocks per wave ---------------
// BM=64, BN=128*NCB, 512 thr = 8 waves (2 row x 4 col), per-wave 32 x 32*NCB.
// WAVE-COALESCED A staging (the r16 fix):
//   fp32 (BKT=64): thread t -> rows t>>4 and (t>>4)+32, col-chunk (t&15)*4
//                  (16 lanes cover one row's 256B contiguously)
//   fp16 BKT=64:   row t>>3, k-chunk (t&7)*8 (8 lanes = 128B contiguous)
//   fp16 BKT=32:   row t>>3, k-chunk (t&7)*4
// LDS fragment layout unchanged from prior rounds (verified vs MFMA operand map).
template<int ACT, int OUTMODE, int BKT, int AFP16, int NCB>
__global__ __launch_bounds__(512) void gemm_mfma(const void* __restrict__ Av,
    const ushort_t* __restrict__ Bh,
    const float* __restrict__ bias, const float* __restrict__ bias2,
    float* __restrict__ C, ushort_t* __restrict__ C16a,
    ushort_t* __restrict__ C16b, int N, int M, int K)
{
  constexpr int NKK = BKT / 16;     // 16-k blocks per step
  __shared__ ushort_t Ah[2][2 * NKK * 512];
  const int t = threadIdx.x;
  const int lane = t & 63;
  const int wid = t >> 6;
  const int wr = wid >> 2;
  const int wc = wid & 3;
  const int row0 = blockIdx.x * 64;
  const int col0 = blockIdx.y * (128 * NCB);
  const int nKB = K >> 4;
  const int nK = K / BKT;
  const int cb0 = (col0 >> 5) + wc * NCB;

  // staging geometry (wave-coalesced)
  int s_r, s_k, sb0, sb1 = 0;
  bool ok0 = false, ok1 = false;
  if constexpr (!AFP16) {
    s_r = t >> 4; s_k = (t & 15) * 4;
    sb0 = (s_k >> 4) * 512 + (s_r + 32 * ((s_k >> 3) & 1)) * 8 + (s_k & 7);
    sb1 = sb0 + NKK * 512;          // row + 32 -> block-row 1
    ok0 = (row0 + s_r) < N;
    ok1 = (row0 + s_r + 32) < N;
  } else if constexpr (BKT == 64) {
    s_r = t >> 3; s_k = (t & 7) * 8;
    sb0 = ((s_r >> 5) * NKK + (s_k >> 4)) * 512 +
          ((s_r & 31) + 32 * ((s_k >> 3) & 1)) * 8;
    ok0 = (row0 + s_r) < N;
  } else {  // fp16, BKT == 32
    s_r = t >> 3; s_k = (t & 7) * 4;
    sb0 = ((s_r >> 5) * NKK + (s_k >> 4)) * 512 +
          ((s_r & 31) + 32 * ((s_k >> 3) & 1)) * 8 + (s_k & 7);
    ok0 = (row0 + s_r) < N;
  }
  const float*    ap0 = (const float*)Av + (size_t)(row0 + s_r) * K + s_k;
  const float*    ap1 = (const float*)Av + (size_t)(row0 + s_r + 32) * K + s_k;
  const ushort_t* aph = (const ushort_t*)Av + (size_t)(row0 + s_r) * K + s_k;

  f32x16 acc0 = {}, acc1 = {};
  float4 f0 = make_float4(0, 0, 0, 0), f1 = make_float4(0, 0, 0, 0);
  half8 h8 = {};
  half4v h4 = {};

  auto aload = [&](int ks) {
    if constexpr (!AFP16) {
      f0 = make_float4(0, 0, 0, 0);
      f1 = make_float4(0, 0, 0, 0);
      if (ok0) f0 = *(const float4*)(ap0 + (size_t)ks * BKT);
      if (ok1) f1 = *(const float4*)(ap1 + (size_t)ks * BKT);
    } else if constexpr (BKT == 64) {
      half8 z = {};
      h8 = ok0 ? *(const half8*)(aph + (size_t)ks * BKT) : z;
    } else {
      half4v z = {};
      h4 = ok0 ? *(const half4v*)(aph + (size_t)ks * BKT) : z;
    }
  };
  auto stage_write = [&](int buf) {
    if constexpr (!AFP16) {
      half4v a, b;
      a[0] = (_Float16)f0.x; a[1] = (_Float16)f0.y;
      a[2] = (_Float16)f0.z; a[3] = (_Float16)f0.w;
      b[0] = (_Float16)f1.x; b[1] = (_Float16)f1.y;
      b[2] = (_Float16)f1.z; b[3] = (_Float16)f1.w;
      *(half4v*)&Ah[buf][sb0] = a;
      *(half4v*)&Ah[buf][sb1] = b;
    } else if constexpr (BKT == 64) {
      *(half8*)&Ah[buf][sb0] = h8;
    } else {
      *(half4v*)&Ah[buf][sb0] = h4;
    }
  };

  aload(0);
  stage_write(0);
  __syncthreads();

  for (int ks = 0; ks < nK; ++ks) {
    const int cur = ks & 1;
    const int nxt = cur ^ 1;
    const bool have_next = (ks + 1 < nK);
    if (have_next) aload(ks + 1);

    #pragma unroll
    for (int kk = 0; kk < NKK; ++kk) {
      const int kbg = ks * NKK + kk;
      half8 ah = *(const half8*)&Ah[cur][(wr * NKK + kk) * 512 + lane * 8];
      const size_t bo0 = ((size_t)(cb0 * nKB + kbg) * 64 + lane) * 8;
      half8 bh0 = *(const half8*)(Bh + bo0);
      acc0 = __builtin_amdgcn_mfma_f32_32x32x16_f16(ah, bh0, acc0, 0, 0, 0);
      if constexpr (NCB == 2) {
        const size_t bo1 = ((size_t)((cb0 + 1) * nKB + kbg) * 64 + lane) * 8;
        half8 bh1 = *(const half8*)(Bh + bo1);
        acc1 = __builtin_amdgcn_mfma_f32_32x32x16_f16(ah, bh1, acc1, 0, 0, 0);
      }
    }

    if (have_next) stage_write(nxt);
    __syncthreads();
  }

  // epilogue: D layout col=lane&31, row=(reg&3)+8*(reg>>2)+4*(lane>>5)
  auto epi = [&](const f32x16& acc, int cb) {
    int cc = cb * 32 + (lane & 31);
    float bv;
    if constexpr (OUTMODE == 3) bv = (cc < 128) ? bias[cc] : bias2[cc - 128];
    else                        bv = (cc < M) ? bias[cc] : 0.f;
    #pragma unroll
    for (int r = 0; r < 16; ++r) {
      int rr = row0 + wr * 32 + (r & 3) + 8 * (r >> 2) + 4 * (lane >> 5);
      if (rr < N && cc < M) {
        float v = acc[r] + bv;
        if (ACT) v = v > 0.f ? v : (__expf(v) - 1.f);
        if constexpr (OUTMODE == 0)      C[(size_t)rr * M + cc] = v;
        else if constexpr (OUTMODE == 1) C16a[(size_t)rr * M + cc] = f2h(v);
        else {
          if (cc < 128) C16a[(size_t)rr * 128 + cc] = f2h(v);
          else          C16b[(size_t)rr * 128 + (cc - 128)] = f2h(v);
        }
      }
    }
  };
  epi(acc0, cb0);
  if constexpr (NCB == 2) epi(acc1, cb0 + 1);
}

// ---------------- CSR build (dst-sorted edge permutation) ---------------------
__global__ void k_degrank(const int* __restrict__ ei, int* __restrict__ deg,
                          int* __restrict__ rank) {
  int e = blockIdx.x * 256 + threadIdx.x;
  if (e >= NE) return;
  int d = ei[NE + e];
  rank[e] = atomicAdd(&deg[d], 1);
}

__global__ __launch_bounds__(256) void k_scan1(const int* __restrict__ deg,
    int* __restrict__ rowstart, int* __restrict__ blocksum) {
  __shared__ int sm[256];
  int b = blockIdx.x, t = threadIdx.x;
  int i = b * 256 + t;
  int v = (i < NN) ? deg[i] : 0;
  sm[t] = v;
  __syncthreads();
  #pragma unroll
  for (int off = 1; off < 256; off <<= 1) {
    int u = (t >= off) ? sm[t - off] : 0;
    __syncthreads();
    sm[t] += u;
    __syncthreads();
  }
  if (i < NN) rowstart[i + 1] = sm[t];
  if (t == 255) blocksum[b] = sm[255];
}

__global__ __launch_bounds__(256) void k_scan2(int* __restrict__ blocksum, int nb) {
  __shared__ int sm[256];
  int t = threadIdx.x;
  int v = (t < nb) ? blocksum[t] : 0;
  sm[t] = v;
  __syncthreads();
  #pragma unroll
  for (int off = 1; off < 256; off <<= 1) {
    int u = (t >= off) ? sm[t - off] : 0;
    __syncthreads();
    sm[t] += u;
    __syncthreads();
  }
  if (t < nb) blocksum[t] = (t == 0) ? 0 : sm[t - 1];
}

__global__ __launch_bounds__(256) void k_scan3(int* __restrict__ rowstart,
    const int* __restrict__ blocksum) {
  int b = blockIdx.x, t = threadIdx.x;
  int i = b * 256 + t;
  if (i == 0) rowstart[0] = 0;
  if (i < NN) rowstart[i + 1] += blocksum[b];
}

__global__ void k_scatter(const int* __restrict__ ei, const int* __restrict__ rowstart,
                          const int* __restrict__ rank, int* __restrict__ srcp) {
  int e = blockIdx.x * 256 + threadIdx.x;
  if (e >= NE) return;
  int d = ei[NE + e];
  srcp[rowstart[d] + rank[e]] = ei[e];
}

// -------- fused GATv2 edge+node, channel-packed, 8-edge pipelined -------------
// Packed-fp16 logit: lrelu(xs+xr) via v_pk_* + v_dot2_f32_f16 att-dot.
__global__ __launch_bounds__(256) void k_gat(const ushort_t* __restrict__ xl,
    const ushort_t* __restrict__ xr, const int* __restrict__ srcp,
    const int* __restrict__ rowstart, const float* __restrict__ att,
    const float* __restrict__ bias, ushort_t* __restrict__ out)
{
  const int g = threadIdx.x >> 5;
  const int c = threadIdx.x & 31;
  const int n = blockIdx.x * 8 + g;
  const int r0 = rowstart[n], r1 = rowstart[n + 1];
  half4v xrh = *(const half4v*)(xr + (size_t)n * 128 + 4 * c);
  const half2v xr01 = {xrh[0], xrh[1]};
  const half2v xr23 = {xrh[2], xrh[3]};
  const float4 atv = *(const float4*)(att + 4 * c);
  const half2v at01 = {(_Float16)atv.x, (_Float16)atv.y};
  const half2v at23 = {(_Float16)atv.z, (_Float16)atv.w};
  const half2v k02 = {(_Float16)0.2f, (_Float16)0.2f};

  float m = -1e30f, ssum = 0.f;
  float a0 = 0.f, a1 = 0.f, a2 = 0.f, a3 = 0.f;

  auto lg = [&](int s, float4& xs) -> float {
    half4v hv = *(const half4v*)(xl + (size_t)s * 128 + 4 * c);
    xs.x = (float)hv[0]; xs.y = (float)hv[1];
    xs.z = (float)hv[2]; xs.w = (float)hv[3];
    half2v u01 = half2v{hv[0], hv[1]} + xr01;
    half2v u23 = half2v{hv[2], hv[3]} + xr23;
    u01 = __builtin_elementwise_max(u01, u01 * k02);
    u23 = __builtin_elementwise_max(u23, u23 * k02);
    float l = fdot2(u01, at01, fdot2(u23, at23, 0.f));
    l += __shfl_xor(l, 1);
    l += __shfl_xor(l, 2);
    l += __shfl_xor(l, 4);
    return l;
  };

  int j = r0;
  for (; j + 8 <= r1; j += 8) {
    int s0 = srcp[j],     s1 = srcp[j + 1], s2 = srcp[j + 2], s3 = srcp[j + 3];
    int s4 = srcp[j + 4], s5 = srcp[j + 5], s6 = srcp[j + 6], s7 = srcp[j + 7];
    float4 x0, x1, x2, x3, x4, x5, x6, x7;
    float l0 = lg(s0, x0), l1 = lg(s1, x1), l2 = lg(s2, x2), l3 = lg(s3, x3);
    float l4 = lg(s4, x4), l5 = lg(s5, x5), l6 = lg(s6, x6), l7 = lg(s7, x7);
    float mloc = fmaxf(fmaxf(fmaxf(l0, l1), fmaxf(l2, l3)),
                       fmaxf(fmaxf(l4, l5), fmaxf(l6, l7)));
    float mn = fmaxf(m, mloc);
    float sc = __expf(m - mn);
    float p0 = __expf(l0 - mn), p1 = __expf(l1 - mn);
    float p2 = __expf(l2 - mn), p3 = __expf(l3 - mn);
    float p4 = __expf(l4 - mn), p5 = __expf(l5 - mn);
    float p6 = __expf(l6 - mn), p7 = __expf(l7 - mn);
    ssum = ssum * sc + (((p0 + p1) + (p2 + p3)) + ((p4 + p5) + (p6 + p7)));
    a0 = a0 * sc + (((p0 * x0.x + p1 * x1.x) + (p2 * x2.x + p3 * x3.x)) +
                    ((p4 * x4.x + p5 * x5.x) + (p6 * x6.x + p7 * x7.x)));
    a1 = a1 * sc + (((p0 * x0.y + p1 * x1.y) + (p2 * x2.y + p3 * x3.y)) +
                    ((p4 * x4.y + p5 * x5.y) + (p6 * x6.y + p7 * x7.y)));
    a2 = a2 * sc + (((p0 * x0.z + p1 * x1.z) + (p2 * x2.z + p3 * x3.z)) +
                    ((p4 * x4.z + p5 * x5.z) + (p6 * x6.z + p7 * x7.z)));
    a3 = a3 * sc + (((p0 * x0.w + p1 * x1.w) + (p2 * x2.w + p3 * x3.w)) +
                    ((p4 * x4.w + p5 * x5.w) + (p6 * x6.w + p7 * x7.w)));
    m = mn;
  }
  for (; j + 4 <= r1; j += 4) {
    int s0 = srcp[j], s1 = srcp[j + 1], s2 = srcp[j + 2], s3 = srcp[j + 3];
    float4 x0, x1, x2, x3;
    float l0 = lg(s0, x0), l1 = lg(s1, x1), l2 = lg(s2, x2), l3 = lg(s3, x3);
    float mloc = fmaxf(fmaxf(l0, l1), fmaxf(l2, l3));
    float mn = fmaxf(m, mloc);
    float sc = __expf(m - mn);
    float p0 = __expf(l0 - mn), p1 = __expf(l1 - mn);
    float p2 = __expf(l2 - mn), p3 = __expf(l3 - mn);
    ssum = ssum * sc + ((p0 + p1) + (p2 + p3));
    a0 = a0 * sc + (p0 * x0.x + p1 * x1.x) + (p2 * x2.x + p3 * x3.x);
    a1 = a1 * sc + (p0 * x0.y + p1 * x1.y) + (p2 * x2.y + p3 * x3.y);
    a2 = a2 * sc + (p0 * x0.z + p1 * x1.z) + (p2 * x2.z + p3 * x3.z);
    a3 = a3 * sc + (p0 * x0.w + p1 * x1.w) + (p2 * x2.w + p3 * x3.w);
    m = mn;
  }
  for (; j < r1; ++j) {
    float4 xs;
    float l = lg(srcp[j], xs);
    float mn = fmaxf(m, l);
    float sc = __expf(m - mn);
    float p = __expf(l - mn);
    ssum = ssum * sc + p;
    a0 = a0 * sc + p * xs.x;
    a1 = a1 * sc + p * xs.y;
    a2 = a2 * sc + p * xs.z;
    a3 = a3 * sc + p * xs.w;
    m = mn;
  }

  const float4 bv = *(const float4*)(bias + 4 * c);
  float rinv = 1.f / (ssum + 1e-16f);
  float o0 = a0 * rinv + bv.x;
  float o1 = a1 * rinv + bv.y;
  float o2 = a2 * rinv + bv.z;
  float o3 = a3 * rinv + bv.w;
  o0 = o0 > 0.f ? o0 : (__expf(o0) - 1.f);
  o1 = o1 > 0.f ? o1 : (__expf(o1) - 1.f);
  o2 = o2 > 0.f ? o2 : (__expf(o2) - 1.f);
  o3 = o3 > 0.f ? o3 : (__expf(o3) - 1.f);
  half4v ov;
  ov[0] = (_Float16)o0; ov[1] = (_Float16)o1;
  ov[2] = (_Float16)o2; ov[3] = (_Float16)o3;
  *(half4v*)(out + (size_t)n * 128 + 4 * c) = ov;
}

__global__ void k_report_ws(float* out, int out_size, float wsz) {
  int i = blockIdx.x * 256 + threadIdx.x;
  if (i < out_size) out[i] = (i == 0) ? wsz : 0.f;
}

// -----------------------------------------------------------------------------
extern "C" void kernel_launch(void* const* d_in, const int* in_sizes, int n_in,
                              void* d_out, int out_size, void* d_ws, size_t ws_size,
                              hipStream_t stream)
{
  const float* x    = (const float*)d_in[0];
  const int*   ei   = (const int*)d_in[1];     // int32 [2,E] row-major
  const float* Wp   = (const float*)d_in[2];  const float* bp    = (const float*)d_in[3];
  const float* Wl1  = (const float*)d_in[4];  const float* bl1   = (const float*)d_in[5];
  const float* Wr1  = (const float*)d_in[6];  const float* br1   = (const float*)d_in[7];
  const float* att1 = (const float*)d_in[8];  const float* bias1 = (const float*)d_in[9];
  const float* Wl2  = (const float*)d_in[10]; const float* bl2   = (const float*)d_in[11];
  const float* Wr2  = (const float*)d_in[12]; const float* br2   = (const float*)d_in[13];
  const float* att2 = (const float*)d_in[14]; const float* bias2 = (const float*)d_in[15];
  const float* W1   = (const float*)d_in[16]; const float* b1    = (const float*)d_in[17];
  const float* W2   = (const float*)d_in[18]; const float* b2    = (const float*)d_in[19];
  float* out = (float*)d_out;

  constexpr size_t NEED = 122300000;
  if (ws_size < NEED) {
    k_report_ws<<<(out_size + 255) / 256, 256, 0, stream>>>(out, out_size, (float)ws_size);
    return;
  }
  char* ws = (char*)d_ws;
  ushort_t* h0h   = (ushort_t*)(ws + 0);          // 50000*256 fp16
  ushort_t* h1h   = h0h;                          // reuse
  ushort_t* h2h   = (ushort_t*)(ws + 25600000);
  ushort_t* xlh   = (ushort_t*)(ws + 51200000);
  ushort_t* xrh   = (ushort_t*)(ws + 76800000);
  ushort_t* h3h   = (ushort_t*)(ws + 102400000);
  ushort_t* wb    = (ushort_t*)(ws + 108800000);
  int*      srcp  = (int*)(ws + 115200000);
  int*      rank  = (int*)(ws + 118400000);
  int*      deg   = (int*)(ws + 121600000);
  int*      rowst = (int*)(ws + 122000000);
  int*      bsum  = (int*)(ws + 122250000);

  ushort_t* Wph  = wb;             // 131072
  ushort_t* WB1h = wb + 131072;    // 65536
  ushort_t* WB2h = wb + 196608;    // 32768
  ushort_t* W1h  = wb + 229376;    // 4096
  ushort_t* W2h  = wb + 233472;    // 1024

  hipMemsetAsync(deg, 0, NN * sizeof(int), stream);

  k_wconv<<<(131072+255)/256, 256, 0, stream>>>(Wp,  Wph,          256, 512, 131072);
  k_wconv<<<(32768+255)/256,  256, 0, stream>>>(Wl1, WB1h,         128, 256, 32768);
  k_wconv<<<(32768+255)/256,  256, 0, stream>>>(Wr1, WB1h + 32768, 128, 256, 32768);
  k_wconv<<<(16384+255)/256,  256, 0, stream>>>(Wl2, WB2h,         128, 128, 16384);
  k_wconv<<<(16384+255)/256,  256, 0, stream>>>(Wr2, WB2h + 16384, 128, 128, 16384);
  k_wconv<<<(4096+255)/256,   256, 0, stream>>>(W1,  W1h,          32,  128, 4096);
  k_wconv<<<(1024+255)/256,   256, 0, stream>>>(W2,  W2h,          10,  32,  1024);

  constexpr int NB = (NN + 255) / 256;
  k_degrank<<<(NE+255)/256, 256, 0, stream>>>(ei, deg, rank);
  k_scan1  <<<NB, 256, 0, stream>>>(deg, rowst, bsum);
  k_scan2  <<<1, 256, 0, stream>>>(bsum, NB);
  k_scan3  <<<NB, 256, 0, stream>>>(rowst, bsum);
  k_scatter<<<(NE+255)/256, 256, 0, stream>>>(ei, rowst, rank, srcp);

  constexpr int GX = (NN + 63) / 64;  // 782

  // projection: h0 = elu(x @ Wp^T + bp) -> fp16, M=256, K=512, single col pass
  gemm_mfma<1,1,64,0,2><<<dim3(GX, 1), 512, 0, stream>>>(
      x, Wph, bp, nullptr, nullptr, h0h, nullptr, NN, 256, 512);

  // GAT layer 1: fused [xl|xr] = h0 @ [Wl1;Wr1]^T, M=256, K=256, single pass
  gemm_mfma<0,3,64,1,2><<<dim3(GX, 1), 512, 0, stream>>>(
      h0h, WB1h, bl1, br1, nullptr, xlh, xrh, NN, 256, 256);
  k_gat<<<NN/8, 256, 0, stream>>>(xlh, xrh, srcp, rowst, att1, bias1, h1h);

  // GAT layer 2: fused, M=256, K=128, single pass
  gemm_mfma<0,3,64,1,2><<<dim3(GX, 1), 512, 0, stream>>>(
      h1h, WB2h, bl2, br2, nullptr, xlh, xrh, NN, 256, 128);
  k_gat<<<NN/8, 256, 0, stream>>>(xlh, xrh, srcp, rowst, att2, bias2, h2h);

  // head MLP: h3 = elu(h2 @ W1^T + b1) fp16; out = h3 @ W2^T + b2 f32
  gemm_mfma<1,1,64,1,1><<<dim3(GX, 1), 512, 0, stream>>>(
      h2h, W1h, b1, nullptr, nullptr, h3h, nullptr, NN, 32, 128);
  gemm_mfma<0,0,32,1,1><<<dim3(GX, 1), 512, 0, stream>>>(
      h3h, W2h, b2, nullptr, out, nullptr, nullptr, NN, 10, 32);
}